// Round 13
// baseline (677.129 us; speedup 1.0000x reference)
//
#include <hip/hip_runtime.h>

#define HW 65536

typedef short bf16x8 __attribute__((ext_vector_type(8)));
typedef float f32x4 __attribute__((ext_vector_type(4)));
typedef unsigned short u16x8 __attribute__((ext_vector_type(8)));

__device__ inline unsigned short f2bf(float v) {
    unsigned u = __float_as_uint(v);
    unsigned r = (u + 0x7FFF + ((u >> 16) & 1)) >> 16;
    return (unsigned short)r;
}
__device__ inline float ubf(unsigned short h) {
    return __uint_as_float(((unsigned)h) << 16);
}
__device__ inline uint4 pack8(const unsigned short* p) {
    uint4 u;
    u.x = (unsigned)p[0] | ((unsigned)p[1] << 16);
    u.y = (unsigned)p[2] | ((unsigned)p[3] << 16);
    u.z = (unsigned)p[4] | ((unsigned)p[5] << 16);
    u.w = (unsigned)p[6] | ((unsigned)p[7] << 16);
    return u;
}
// pfch is tiled: offset(c, n) = (n>>5)*4096 + c*32 + (n&31)
__device__ inline size_t pfchoff(int c, int n) {
    return ((size_t)(n >> 5) << 12) + (c << 5) + (n & 31);
}

// ---------------------------------------------------------------------------
// Merge 7/5/3 kernels into one 7x7; emit bf16 hi/lo in A-FRAGMENT LANE ORDER.
// ---------------------------------------------------------------------------
__global__ void wmerge_kernel(const float* __restrict__ k7, const float* __restrict__ k5,
                              const float* __restrict__ k3, int Cin, int nch,
                              unsigned short* __restrict__ wTh, unsigned short* __restrict__ wTl)
{
    int idx = blockIdx.x * 256 + threadIdx.x;
    int total = 49 * nch * 1024;
    if (idx >= total) return;
    int e = idx & 7;
    int lane = (idx >> 3) & 63;
    int octile = (idx >> 9) & 1;
    int chunk = (idx >> 10) % nch;
    int tap = idx / (nch << 10);
    int oc = octile * 16 + (lane & 15);
    int ci = chunk * 32 + (lane >> 4) * 8 + e;
    int ky = tap / 7, kx = tap % 7;
    float v = 0.f;
    if (ci < Cin) {
        v = k7[(oc * Cin + ci) * 49 + tap];
        if (ky >= 1 && ky <= 5 && kx >= 1 && kx <= 5)
            v += k5[(oc * Cin + ci) * 25 + (ky - 1) * 5 + (kx - 1)];
        if (ky >= 2 && ky <= 4 && kx >= 2 && kx <= 4)
            v += k3[(oc * Cin + ci) * 9 + (ky - 2) * 3 + (kx - 2)];
    }
    unsigned short h = f2bf(v);
    wTh[idx] = h;
    wTl[idx] = f2bf(v - ubf(h));
}

// ---------------------------------------------------------------------------
// x [103][HW] fp32 -> xT [n][128] bf16 hi/lo and pfch (tiled) rows 0..102
// ---------------------------------------------------------------------------
__global__ __launch_bounds__(256) void transpose_kernel(
    const float* __restrict__ x,
    unsigned short* __restrict__ xTh, unsigned short* __restrict__ xTl,
    unsigned short* __restrict__ pfch)
{
    __shared__ float buf[64 * 105];
    int t = threadIdx.x;
    int px0 = blockIdx.x * 64;
    for (int i = t; i < 103 * 64; i += 256) {
        int c = i >> 6, lane = i & 63;
        int n = px0 + lane;
        float v = x[(size_t)c * HW + n];
        buf[lane * 105 + c] = v;
        pfch[pfchoff(c, n)] = f2bf(v);
    }
    __syncthreads();
    int px = t >> 2, seg = t & 3;
    unsigned short h[32], l[32];
#pragma unroll
    for (int j = 0; j < 32; ++j) {
        int c = seg * 32 + j;
        float v = (c < 103) ? buf[px * 105 + c] : 0.f;
        h[j] = f2bf(v);
        l[j] = f2bf(v - ubf(h[j]));
    }
    size_t base = (size_t)(px0 + px) * 128 + seg * 32;
#pragma unroll
    for (int k = 0; k < 4; ++k) {
        *(uint4*)(xTh + base + k * 8) = pack8(h + k * 8);
        *(uint4*)(xTl + base + k * 8) = pack8(l + k * 8);
    }
}

// ---------------------------------------------------------------------------
// Implicit-GEMM 7x7 conv, MFMA 16x16x32 bf16, 3-phase hi/lo.
// 4 rows per wave (16-row block tile). Weights in LDS 3-tap ring.
// Grid (256, 2) with z-split work ranges. XCD-aware tile swizzle.
// ---------------------------------------------------------------------------
__global__ __launch_bounds__(256) void convm_kernel(
    const unsigned short* __restrict__ actH, const unsigned short* __restrict__ actL,
    int Cs,
    const unsigned short* __restrict__ wTh, const unsigned short* __restrict__ wTl,
    int nchw,
    int c0a, int c1a, int t0a, int t1a,
    int c0b, int c1b, int t0b, int t1b,
    float* __restrict__ ypart)
{
    __shared__ __align__(16) unsigned short sH[22 * 704];
    __shared__ __align__(16) unsigned short sL[22 * 704];
    __shared__ __align__(16) unsigned short sW[3 * 2048];
    int t = threadIdx.x;
    int w = t >> 6, l = t & 63;
    int lc = l & 15, lg = l >> 4;
    int bid = blockIdx.x;
    int swz = (bid & 7) * 32 + (bid >> 3);   // bijective: 256 = 8 XCDs x 32
    int bx = swz & 15, byy = swz >> 4;
    int x0 = bx * 16, y0 = byy * 16;
    int z = blockIdx.y;
    int ch0 = z ? c0b : c0a, ch1 = z ? c1b : c1a;
    int tap0 = z ? t0b : t0a, tap1 = z ? t1b : t1a;
    float* yp = ypart + (size_t)z * 32 * HW;

    f32x4 a_hh[2][4], a_lh[2][4], a_hl[2][4];   // [oc-tile][row]
#pragma unroll
    for (int ot = 0; ot < 2; ++ot)
#pragma unroll
        for (int rr = 0; rr < 4; ++rr)
#pragma unroll
            for (int r = 0; r < 4; ++r) {
                a_hh[ot][rr][r] = 0.f; a_lh[ot][rr][r] = 0.f; a_hl[ot][rr][r] = 0.f;
            }

    for (int ch = ch0; ch < ch1; ++ch) {
        int ci0 = ch * 32;
        __syncthreads();                // protect sH/sL from prior reads
        for (int i = t; i < 2 * 22 * 88; i += 256) {
            int pl = (i >= 22 * 88) ? 1 : 0;
            int j = pl ? i - 22 * 88 : i;
            int row = j / 88;
            int rem = j - row * 88;
            int px = rem >> 2, q = rem & 3;
            int gy = y0 - 3 + row, gx = x0 - 3 + px;
            uint4 v = {0u, 0u, 0u, 0u};
            if (gy >= 0 && gy < 256 && gx >= 0 && gx < 256) {
                const unsigned short* src = pl ? actL : actH;
                v = *(const uint4*)(src + (size_t)(gy * 256 + gx) * Cs + ci0 + q * 8);
            }
            unsigned short* dst = pl ? sL : sH;
            *(uint4*)(dst + row * 704 + q * 176 + px * 8) = v;
        }

        for (int g = tap0; g < tap1; g += 3) {
            int ge = g + 3; if (ge > tap1) ge = tap1;
            if (g > tap0) __syncthreads();      // protect sW from prior group reads
            for (int i = t; i < (ge - g) * 256; i += 256) {
                int tp = i >> 8, r = i & 255;
                const unsigned short* src = (r < 128) ? wTh : wTl;
                *(uint4*)(sW + tp * 2048 + r * 8) =
                    *(const uint4*)(src + ((size_t)((g + tp) * nchw + ch)) * 1024 + (r & 127) * 8);
            }
            __syncthreads();

            for (int tap = g; tap < ge; ++tap) {
                const unsigned short* wb = sW + (tap - g) * 2048 + l * 8;
                bf16x8 ah0 = *(const bf16x8*)(wb);
                bf16x8 ah1 = *(const bf16x8*)(wb + 512);
                bf16x8 al0 = *(const bf16x8*)(wb + 1024);
                bf16x8 al1 = *(const bf16x8*)(wb + 1536);
                int ky = tap / 7;
                int kx = tap - ky * 7;
#pragma unroll
                for (int rr = 0; rr < 4; ++rr) {
                    int off = (w * 4 + rr + ky) * 704 + lg * 176 + (lc + kx) * 8;
                    bf16x8 xh = *(const bf16x8*)(sH + off);
                    bf16x8 xl = *(const bf16x8*)(sL + off);
                    a_hh[0][rr] = __builtin_amdgcn_mfma_f32_16x16x32_bf16(ah0, xh, a_hh[0][rr], 0, 0, 0);
                    a_hh[1][rr] = __builtin_amdgcn_mfma_f32_16x16x32_bf16(ah1, xh, a_hh[1][rr], 0, 0, 0);
                    a_lh[0][rr] = __builtin_amdgcn_mfma_f32_16x16x32_bf16(al0, xh, a_lh[0][rr], 0, 0, 0);
                    a_lh[1][rr] = __builtin_amdgcn_mfma_f32_16x16x32_bf16(al1, xh, a_lh[1][rr], 0, 0, 0);
                    a_hl[0][rr] = __builtin_amdgcn_mfma_f32_16x16x32_bf16(ah0, xl, a_hl[0][rr], 0, 0, 0);
                    a_hl[1][rr] = __builtin_amdgcn_mfma_f32_16x16x32_bf16(ah1, xl, a_hl[1][rr], 0, 0, 0);
                }
            }
        }
    }

#pragma unroll
    for (int ot = 0; ot < 2; ++ot)
#pragma unroll
        for (int rr = 0; rr < 4; ++rr) {
            int n = (y0 + w * 4 + rr) * 256 + x0 + lc;
#pragma unroll
            for (int r = 0; r < 4; ++r) {
                int oc = ot * 16 + lg * 4 + r;
                yp[(size_t)oc * HW + n] = a_hh[ot][rr][r] + a_lh[ot][rr][r] + a_hl[ot][rr][r];
            }
        }
}

// ---------------------------------------------------------------------------
// Sum 2 partial planes -> ysum, with fused per-channel sum/sumsq stats.
// ---------------------------------------------------------------------------
__global__ __launch_bounds__(256) void reduce2_kernel(
    const float* __restrict__ p0, const float* __restrict__ p1,
    float* __restrict__ y, float* __restrict__ ssum, float* __restrict__ ssq)
{
    int c = blockIdx.x >> 5, seg = blockIdx.x & 31;
    int base = c * HW + seg * 2048 + threadIdx.x * 8;
    float s = 0.f, q = 0.f;
#pragma unroll
    for (int h = 0; h < 2; ++h) {
        int o = base + h * 4;
        float4 a0 = *(const float4*)&p0[o];
        float4 a1 = *(const float4*)&p1[o];
        float4 v;
        v.x = a0.x + a1.x; v.y = a0.y + a1.y;
        v.z = a0.z + a1.z; v.w = a0.w + a1.w;
        *(float4*)&y[o] = v;
        s += v.x + v.y + v.z + v.w;
        q = fmaf(v.x, v.x, q); q = fmaf(v.y, v.y, q);
        q = fmaf(v.z, v.z, q); q = fmaf(v.w, v.w, q);
    }
#pragma unroll
    for (int d = 32; d >= 1; d >>= 1) {
        s += __shfl_down(s, d);
        q += __shfl_down(q, d);
    }
    __shared__ float ls[4], lq[4];
    int w = threadIdx.x >> 6;
    if ((threadIdx.x & 63) == 0) { ls[w] = s; lq[w] = q; }
    __syncthreads();
    if (threadIdx.x == 0) {
        atomicAdd(&ssum[c], ls[0] + ls[1] + ls[2] + ls[3]);
        atomicAdd(&ssq[c], lq[0] + lq[1] + lq[2] + lq[3]);
    }
}

__global__ void bnp_kernel(const float* __restrict__ ssum, const float* __restrict__ ssq,
                           const float* __restrict__ g, const float* __restrict__ beta,
                           float* __restrict__ scl, float* __restrict__ shf)
{
    int c = threadIdx.x;
    float mu  = ssum[c] * (1.f / 65536.f);
    float var = ssq[c] * (1.f / 65536.f) - mu * mu;
    float s = g[c] * rsqrtf(var + 1e-5f);
    scl[c] = s;
    shf[c] = beta[c] - mu * s;
}

// ---------------------------------------------------------------------------
// BN + ReLU + write channel-last bf16 hi/lo
// ---------------------------------------------------------------------------
__global__ __launch_bounds__(256) void bna_kernel(
    const float* __restrict__ yraw, const float* __restrict__ scl, const float* __restrict__ shf,
    unsigned short* __restrict__ aH, unsigned short* __restrict__ aL, int Cs, int slot0)
{
    int t = threadIdx.x;
    int lane = t & 63, cg = t >> 6;
    int px = blockIdx.x * 64 + lane;
    unsigned short h[8], l[8];
#pragma unroll
    for (int j = 0; j < 8; ++j) {
        int c = cg * 8 + j;
        float v = fmaxf(yraw[(size_t)c * HW + px] * scl[c] + shf[c], 0.f);
        h[j] = f2bf(v);
        l[j] = f2bf(v - ubf(h[j]));
    }
    *(uint4*)(aH + (size_t)px * Cs + slot0 + cg * 8) = pack8(h);
    *(uint4*)(aL + (size_t)px * Cs + slot0 + cg * 8) = pack8(l);
}

// ---------------------------------------------------------------------------
// 1x1 conv (96->15) + ReLU; writes pf slots 103..127 of xT and pfch (tiled)
// ---------------------------------------------------------------------------
__global__ __launch_bounds__(256) void feat_kernel(
    const unsigned short* __restrict__ a12H, const unsigned short* __restrict__ a12L,
    const unsigned short* __restrict__ a3H, const unsigned short* __restrict__ a3L,
    const float* __restrict__ w, const float* __restrict__ b,
    unsigned short* __restrict__ xTh, unsigned short* __restrict__ xTl,
    unsigned short* __restrict__ pfch)
{
    int n = blockIdx.x * 256 + threadIdx.x;
    float facc[15];
#pragma unroll
    for (int oc = 0; oc < 15; ++oc) facc[oc] = b[oc];

#pragma unroll
    for (int k = 0; k < 12; ++k) {
        uint4 uh, ul;
        if (k < 8) {
            uh = *(const uint4*)(a12H + (size_t)n * 64 + k * 8);
            ul = *(const uint4*)(a12L + (size_t)n * 64 + k * 8);
        } else {
            uh = *(const uint4*)(a3H + (size_t)n * 32 + (k - 8) * 8);
            ul = *(const uint4*)(a3L + (size_t)n * 32 + (k - 8) * 8);
        }
        unsigned hw_[4] = {uh.x, uh.y, uh.z, uh.w};
        unsigned lw_[4] = {ul.x, ul.y, ul.z, ul.w};
#pragma unroll
        for (int j = 0; j < 8; ++j) {
            unsigned short hh = (unsigned short)(hw_[j >> 1] >> ((j & 1) * 16));
            unsigned short ll = (unsigned short)(lw_[j >> 1] >> ((j & 1) * 16));
            float av = ubf(hh) + ubf(ll);
#pragma unroll
            for (int oc = 0; oc < 15; ++oc)
                facc[oc] = fmaf(av, w[oc * 96 + k * 8 + j], facc[oc]);
        }
    }
    unsigned short fh[16], fl[16];
#pragma unroll
    for (int oc = 0; oc < 15; ++oc) {
        float v = fmaxf(facc[oc], 0.f);
        fh[oc] = f2bf(v);
        fl[oc] = f2bf(v - ubf(fh[oc]));
    }
    fh[15] = 0; fl[15] = 0;

    size_t base = (size_t)n * 128;
    uint4 h0 = *(const uint4*)(xTh + base + 96);
    uint4 l0 = *(const uint4*)(xTl + base + 96);
    h0.w = (h0.w & 0xFFFFu) | ((unsigned)fh[0] << 16);
    l0.w = (l0.w & 0xFFFFu) | ((unsigned)fl[0] << 16);
    *(uint4*)(xTh + base + 96) = h0;
    *(uint4*)(xTl + base + 96) = l0;
    *(uint4*)(xTh + base + 104) = pack8(fh + 1);
    *(uint4*)(xTl + base + 104) = pack8(fl + 1);
    unsigned short t2h[8], t2l[8];
#pragma unroll
    for (int j = 0; j < 8; ++j) {
        t2h[j] = (j < 6) ? fh[9 + j] : (unsigned short)0;
        t2l[j] = (j < 6) ? fl[9 + j] : (unsigned short)0;
    }
    *(uint4*)(xTh + base + 112) = pack8(t2h);
    *(uint4*)(xTl + base + 112) = pack8(t2l);
    unsigned short t3h[8] = {0, 0, 0, 0, 0, 0, 0, 0x3F80};
    unsigned short t3l[8] = {0, 0, 0, 0, 0, 0, 0, 0};
    *(uint4*)(xTh + base + 120) = pack8(t3h);
    *(uint4*)(xTl + base + 120) = pack8(t3l);

#pragma unroll
    for (int k2 = 0; k2 < 15; ++k2)
        pfch[pfchoff(103 + k2, n)] = fh[k2];
    pfch[pfchoff(118, n)] = 0x3F80;
#pragma unroll
    for (int c = 119; c < 128; ++c)
        pfch[pfchoff(c, n)] = 0;
}

// ---------------------------------------------------------------------------
// c0: per-superpixel channel sums -> cn_fin[s][128]
// ---------------------------------------------------------------------------
__global__ __launch_bounds__(256) void c0_kernel(
    const unsigned short* __restrict__ pfTh, const unsigned short* __restrict__ pfTl,
    float* __restrict__ cn_fin)
{
    int s = blockIdx.x;
    int sy = s >> 4, sx = s & 15;
    int t = threadIdx.x;
    int xx = t >> 4;
    int cs = (t & 15) * 8;

    float acc[8];
#pragma unroll
    for (int j = 0; j < 8; ++j) acc[j] = 0.f;

    for (int yy = 0; yy < 16; ++yy) {
        int n = (sy * 16 + yy) * 256 + sx * 16 + xx;
        u16x8 h = *(const u16x8*)(pfTh + (size_t)n * 128 + cs);
        u16x8 l = *(const u16x8*)(pfTl + (size_t)n * 128 + cs);
#pragma unroll
        for (int j = 0; j < 8; ++j)
            acc[j] += ubf(h[j]) + ubf(l[j]);
    }
#pragma unroll
    for (int j = 0; j < 8; ++j) {
        acc[j] += __shfl_xor(acc[j], 16);
        acc[j] += __shfl_xor(acc[j], 32);
    }
    __shared__ float red[4][128];
    int w = t >> 6;
    if ((t & 63) < 16) {
#pragma unroll
        for (int j = 0; j < 8; ++j)
            red[w][(t & 15) * 8 + j] = acc[j];
    }
    __syncthreads();
    if (t < 128)
        cn_fin[s * 128 + t] = red[0][t] + red[1][t] + red[2][t] + red[3][t];
}

// ---------------------------------------------------------------------------
// reduce_cn: cn_part [512][32768] -> cn_mid [8][32768]
// ---------------------------------------------------------------------------
__global__ __launch_bounds__(256) void reduce_cn(
    const float* __restrict__ cn_part, float* __restrict__ cn_mid)
{
    int o = blockIdx.x * 256 + threadIdx.x;
    int k0 = blockIdx.y * 64;
    float a = 0.f;
    for (int k = k0; k < k0 + 64; ++k)
        a += cn_part[(size_t)k * 32768 + o];
    cn_mid[(size_t)blockIdx.y * 32768 + o] = a;
}

// ---------------------------------------------------------------------------
// prep: centroids -> chiT/cloT [s][128]; slot 127 = -0.5*|c|^2.
// src has nmid stacked [32768] planes to be summed.
// ---------------------------------------------------------------------------
__global__ __launch_bounds__(128) void prep_kernel(
    const float* __restrict__ src, int nmid,
    unsigned short* __restrict__ chiT, unsigned short* __restrict__ cloT,
    float scale0, int use_qsum)
{
    int s = blockIdx.x, c = threadIdx.x;
    float v = 0.f, q118 = 0.f;
    for (int m = 0; m < nmid; ++m) {
        v += src[(size_t)m * 32768 + s * 128 + c];
        q118 += src[(size_t)m * 32768 + s * 128 + 118];
    }
    float inv = use_qsum ? 1.f / (q118 + 1e-8f) : scale0;
    v = (c < 118) ? v * inv : 0.f;
    float a = v * v;
#pragma unroll
    for (int d = 1; d < 64; d <<= 1) a += __shfl_xor(a, d);
    __shared__ float red[2];
    if ((c & 63) == 0) red[c >> 6] = a;
    __syncthreads();
    float tot = red[0] + red[1];
    unsigned short h, lo;
    if (c == 127) {
        float m2 = -0.5f * tot;
        h = f2bf(m2);
        lo = f2bf(m2 - ubf(h));
    } else {
        h = f2bf(v);
        lo = f2bf(v - ubf(h));
    }
    chiT[s * 128 + c] = h;
    cloT[s * 128 + c] = lo;
}

// ---------------------------------------------------------------------------
// FUSED dist+cn, 32 KB LDS. pfch reads are now TILED (coalesced 1KB/instr).
// ---------------------------------------------------------------------------
__global__ __launch_bounds__(256) void distcn_kernel(
    const unsigned short* __restrict__ chiT, const unsigned short* __restrict__ cloT,
    const unsigned short* __restrict__ pfTh, const unsigned short* __restrict__ pfTl,
    const unsigned short* __restrict__ pfch,
    float* __restrict__ cn_part, float* __restrict__ qf, int final_mode)
{
    __shared__ __align__(16) unsigned short sA[16384];  // 32 KB: A-stage / sQ-half
    unsigned short* sQ = sA;
    int t = threadIdx.x;
    int w = t >> 6, l = t & 63;
    int lc = l & 15, lg = l >> 4;
    int nblk = blockIdx.x * 128;
    int n0 = nblk + w * 32;

    // preload all B fragments (each xT element read exactly once)
    bf16x8 bh[4][2], bl[4][2];
#pragma unroll
    for (int ks = 0; ks < 4; ++ks) {
        int kb = ks * 32 + 8 * lg;
        bh[ks][0] = *(const bf16x8*)(pfTh + (size_t)(n0 + lc) * 128 + kb);
        bh[ks][1] = *(const bf16x8*)(pfTh + (size_t)(n0 + 16 + lc) * 128 + kb);
        bl[ks][0] = *(const bf16x8*)(pfTl + (size_t)(n0 + lc) * 128 + kb);
        bl[ks][1] = *(const bf16x8*)(pfTl + (size_t)(n0 + 16 + lc) * 128 + kb);
    }

    f32x4 acc[16][2];
#pragma unroll
    for (int i = 0; i < 16; ++i)
#pragma unroll
        for (int g = 0; g < 2; ++g)
#pragma unroll
            for (int j = 0; j < 4; ++j) acc[i][g][j] = 0.f;

#pragma unroll
    for (int ro = 0; ro < 4; ++ro) {
        __syncthreads();
        for (int i = t; i < 2048; i += 256) {
            int plane = i >> 10;
            int ii = i & 1023;
            int sl = ii >> 4;
            int j = ii & 15;
            const unsigned short* src = plane ? cloT : chiT;
            uint4 v = *(const uint4*)(src + (((size_t)(ro * 64 + sl)) << 7) + j * 8);
            int ds = ((sl << 7) + j * 8) ^ ((sl & 7) << 3);
            *(uint4*)(sA + plane * 8192 + ds) = v;
        }
        __syncthreads();

#pragma unroll
        for (int s4 = 0; s4 < 4; ++s4) {
            const int st = ro * 4 + s4;
#pragma unroll
            for (int ks = 0; ks < 4; ++ks) {
                int e0 = (((s4 * 16 + lc) << 7) + ks * 32 + lg * 8) ^ ((lc & 7) << 3);
                bf16x8 ah = *(const bf16x8*)(sA + e0);
                bf16x8 al = *(const bf16x8*)(sA + 8192 + e0);
                acc[st][0] = __builtin_amdgcn_mfma_f32_16x16x32_bf16(ah, bh[ks][0], acc[st][0], 0, 0, 0);
                acc[st][0] = __builtin_amdgcn_mfma_f32_16x16x32_bf16(al, bh[ks][0], acc[st][0], 0, 0, 0);
                acc[st][0] = __builtin_amdgcn_mfma_f32_16x16x32_bf16(ah, bl[ks][0], acc[st][0], 0, 0, 0);
                acc[st][1] = __builtin_amdgcn_mfma_f32_16x16x32_bf16(ah, bh[ks][1], acc[st][1], 0, 0, 0);
                acc[st][1] = __builtin_amdgcn_mfma_f32_16x16x32_bf16(al, bh[ks][1], acc[st][1], 0, 0, 0);
                acc[st][1] = __builtin_amdgcn_mfma_f32_16x16x32_bf16(ah, bl[ks][1], acc[st][1], 0, 0, 0);
            }
        }
    }

    float m0 = -1e30f, m1 = -1e30f;
#pragma unroll
    for (int st = 0; st < 16; ++st)
#pragma unroll
        for (int r = 0; r < 4; ++r) {
            m0 = fmaxf(m0, acc[st][0][r]);
            m1 = fmaxf(m1, acc[st][1][r]);
        }
    m0 = fmaxf(m0, __shfl_xor(m0, 16)); m0 = fmaxf(m0, __shfl_xor(m0, 32));
    m1 = fmaxf(m1, __shfl_xor(m1, 16)); m1 = fmaxf(m1, __shfl_xor(m1, 32));

    float s0 = 0.f, s1 = 0.f;
#pragma unroll
    for (int st = 0; st < 16; ++st)
#pragma unroll
        for (int r = 0; r < 4; ++r) {
            float e0 = __expf(2.f * (acc[st][0][r] - m0));
            float e1 = __expf(2.f * (acc[st][1][r] - m1));
            acc[st][0][r] = e0; acc[st][1][r] = e1;
            s0 += e0; s1 += e1;
        }
    s0 += __shfl_xor(s0, 16); s0 += __shfl_xor(s0, 32);
    s1 += __shfl_xor(s1, 16); s1 += __shfl_xor(s1, 32);
    float i0 = 1.f / s0, i1 = 1.f / s1;

    if (final_mode) {
        int nA = n0 + lc, nB = n0 + 16 + lc;
#pragma unroll
        for (int st = 0; st < 16; ++st)
#pragma unroll
            for (int r = 0; r < 4; ++r) {
                int s = st * 16 + lg * 4 + r;
                qf[(size_t)s * HW + nA] = acc[st][0][r] * i0;
                qf[(size_t)s * HW + nB] = acc[st][1][r] * i1;
            }
        return;
    }

    // phases 2/3 in two s-halves (sQ-half = 128 s x 128 px bf16 = 32 KB)
#pragma unroll
    for (int h = 0; h < 2; ++h) {
        __syncthreads();    // previous sA contents (stage or sQ-half) dead
#pragma unroll
        for (int st8 = 0; st8 < 8; ++st8) {
            const int st = h * 8 + st8;
#pragma unroll
            for (int g = 0; g < 2; ++g) {
                float iv = g ? i1 : i0;
#pragma unroll
                for (int r = 0; r < 4; ++r) {
                    int idx = ((st8 * 4 + w) * 64 + (g * 2 + (lc >> 3)) * 16 + lg * 4 + r) * 8 + (lc & 7);
                    sQ[idx] = f2bf(acc[st][g][r] * iv);
                }
            }
        }
        __syncthreads();

        // phase 3 for this half: wave w covers c in [w*32, w*32+32)
        f32x4 a2[8][2];
#pragma unroll
        for (int i = 0; i < 8; ++i)
#pragma unroll
            for (int ct = 0; ct < 2; ++ct)
#pragma unroll
                for (int j = 0; j < 4; ++j) a2[i][ct][j] = 0.f;

#pragma unroll
        for (int kc = 0; kc < 4; ++kc) {
            // tiled pfch: tile = (nblk>>5)+kc, fragment k = lg*8+e (contiguous)
            size_t tb = ((size_t)((nblk >> 5) + kc) << 12) + lg * 8;
            bf16x8 b0 = *(const bf16x8*)(pfch + tb + (w * 32 + lc) * 32);
            bf16x8 b1 = *(const bf16x8*)(pfch + tb + (w * 32 + 16 + lc) * 32);
#pragma unroll
            for (int st8 = 0; st8 < 8; ++st8) {
                bf16x8 afr = *(const bf16x8*)(sQ + ((size_t)(st8 * 4 + kc) * 64 + l) * 8);
                a2[st8][0] = __builtin_amdgcn_mfma_f32_16x16x32_bf16(afr, b0, a2[st8][0], 0, 0, 0);
                a2[st8][1] = __builtin_amdgcn_mfma_f32_16x16x32_bf16(afr, b1, a2[st8][1], 0, 0, 0);
            }
        }

        float* out = cn_part + (size_t)blockIdx.x * 32768;
#pragma unroll
        for (int st8 = 0; st8 < 8; ++st8)
#pragma unroll
            for (int ct = 0; ct < 2; ++ct)
#pragma unroll
                for (int r = 0; r < 4; ++r) {
                    int s = (h * 8 + st8) * 16 + lg * 4 + r;
                    int c = w * 32 + ct * 16 + lc;
                    out[s * 128 + c] = a2[st8][ct][r];
                }
    }
}

// ---------------------------------------------------------------------------
extern "C" void kernel_launch(void* const* d_in, const int* in_sizes, int n_in,
                              void* d_out, int out_size, void* d_ws, size_t ws_size,
                              hipStream_t stream)
{
    const float* x     = (const float*)d_in[0];
    const float* s1k7  = (const float*)d_in[1];
    const float* s1k5  = (const float*)d_in[2];
    const float* s1k3  = (const float*)d_in[3];
    const float* s1g   = (const float*)d_in[5];
    const float* s1be  = (const float*)d_in[6];
    const float* s2k7  = (const float*)d_in[7];
    const float* s2k5  = (const float*)d_in[8];
    const float* s2k3  = (const float*)d_in[9];
    const float* s2g   = (const float*)d_in[11];
    const float* s2be  = (const float*)d_in[12];
    const float* s3k7  = (const float*)d_in[13];
    const float* s3k5  = (const float*)d_in[14];
    const float* s3k3  = (const float*)d_in[15];
    const float* s3g   = (const float*)d_in[17];
    const float* s3be  = (const float*)d_in[18];
    const float* outw  = (const float*)d_in[19];
    const float* outb  = (const float*)d_in[20];

    float* ws = (float*)d_ws;
    size_t off = 0;
    unsigned short* wT1h = (unsigned short*)(ws + off); off += 100352;
    unsigned short* wT1l = (unsigned short*)(ws + off); off += 100352;
    unsigned short* wT2h = (unsigned short*)(ws + off); off += 25088;
    unsigned short* wT2l = (unsigned short*)(ws + off); off += 25088;
    unsigned short* wT3h = (unsigned short*)(ws + off); off += 50176;
    unsigned short* wT3l = (unsigned short*)(ws + off); off += 50176;
    float* stats = ws + off; off += 192;
    float* bn    = ws + off; off += 192;
    float* cn_fin= ws + off; off += 32768;
    float* cn_mid= ws + off; off += 262144;
    unsigned short* chiT = (unsigned short*)(ws + off); off += 16384;
    unsigned short* cloT = (unsigned short*)(ws + off); off += 16384;
    unsigned short* xTh  = (unsigned short*)(ws + off); off += 4194304;
    unsigned short* xTl  = (unsigned short*)(ws + off); off += 4194304;
    unsigned short* pfch = (unsigned short*)(ws + off); off += 4194304;
    unsigned short* a12H = (unsigned short*)(ws + off); off += 2097152;
    unsigned short* a12L = (unsigned short*)(ws + off); off += 2097152;

    char* ob = (char*)d_out;
    float* p0   = (float*)ob;
    float* p1   = (float*)(ob + (size_t)8 * 1024 * 1024);
    float* ysum = (float*)(ob + (size_t)16 * 1024 * 1024);
    float* cn_part = (float*)ob;
    float* qf = (float*)ob;
    unsigned short* a3H = (unsigned short*)(ob + (size_t)32 * 1024 * 1024);
    unsigned short* a3L = a3H + (size_t)HW * 32;

    hipMemsetAsync(stats, 0, 192 * sizeof(float), stream);
    wmerge_kernel<<<(49 * 4 * 1024 + 255) / 256, 256, 0, stream>>>(s1k7, s1k5, s1k3, 103, 4, wT1h, wT1l);
    wmerge_kernel<<<(49 * 1 * 1024 + 255) / 256, 256, 0, stream>>>(s2k7, s2k5, s2k3, 32, 1, wT2h, wT2l);
    wmerge_kernel<<<(49 * 2 * 1024 + 255) / 256, 256, 0, stream>>>(s3k7, s3k5, s3k3, 64, 2, wT3h, wT3l);

    transpose_kernel<<<1024, 256, 0, stream>>>(x, xTh, xTl, pfch);

    convm_kernel<<<dim3(256, 2), 256, 0, stream>>>(xTh, xTl, 128, wT1h, wT1l, 4,
                                                   0, 2, 0, 49, 2, 4, 0, 49, p0);
    reduce2_kernel<<<1024, 256, 0, stream>>>(p0, p1, ysum, stats + 0, stats + 32);
    bnp_kernel<<<1, 32, 0, stream>>>(stats + 0, stats + 32, s1g, s1be, bn + 0, bn + 32);
    bna_kernel<<<1024, 256, 0, stream>>>(ysum, bn + 0, bn + 32, a12H, a12L, 64, 0);

    convm_kernel<<<dim3(256, 2), 256, 0, stream>>>(a12H, a12L, 64, wT2h, wT2l, 1,
                                                   0, 1, 0, 25, 0, 1, 25, 49, p0);
    reduce2_kernel<<<1024, 256, 0, stream>>>(p0, p1, ysum, stats + 64, stats + 96);
    bnp_kernel<<<1, 32, 0, stream>>>(stats + 64, stats + 96, s2g, s2be, bn + 64, bn + 96);
    bna_kernel<<<1024, 256, 0, stream>>>(ysum, bn + 64, bn + 96, a12H, a12L, 64, 32);

    convm_kernel<<<dim3(256, 2), 256, 0, stream>>>(a12H, a12L, 64, wT3h, wT3l, 2,
                                                   0, 1, 0, 49, 1, 2, 0, 49, p0);
    reduce2_kernel<<<1024, 256, 0, stream>>>(p0, p1, ysum, stats + 128, stats + 160);
    bnp_kernel<<<1, 32, 0, stream>>>(stats + 128, stats + 160, s3g, s3be, bn + 128, bn + 160);
    bna_kernel<<<1024, 256, 0, stream>>>(ysum, bn + 128, bn + 160, a3H, a3L, 32, 0);

    feat_kernel<<<256, 256, 0, stream>>>(a12H, a12L, a3H, a3L, outw, outb, xTh, xTl, pfch);
    c0_kernel<<<256, 256, 0, stream>>>(xTh, xTl, cn_fin);
    prep_kernel<<<256, 128, 0, stream>>>(cn_fin, 1, chiT, cloT, 1.f / 256.f, 0);

    for (int it = 0; it < 5; ++it) {
        distcn_kernel<<<512, 256, 0, stream>>>(chiT, cloT, xTh, xTl, pfch, cn_part, qf, 0);
        reduce_cn<<<dim3(128, 8), 256, 0, stream>>>(cn_part, cn_mid);
        prep_kernel<<<256, 128, 0, stream>>>(cn_mid, 8, chiT, cloT, 0.f, 1);
    }
    distcn_kernel<<<512, 256, 0, stream>>>(chiT, cloT, xTh, xTl, pfch, cn_part, qf, 1);
}

// Round 14
// 512.785 us; speedup vs baseline: 1.3205x; 1.3205x over previous
//
#include <hip/hip_runtime.h>

#define HW 65536

typedef short bf16x8 __attribute__((ext_vector_type(8)));
typedef float f32x4 __attribute__((ext_vector_type(4)));
typedef unsigned short u16x8 __attribute__((ext_vector_type(8)));

__device__ inline unsigned short f2bf(float v) {
    unsigned u = __float_as_uint(v);
    unsigned r = (u + 0x7FFF + ((u >> 16) & 1)) >> 16;
    return (unsigned short)r;
}
__device__ inline float ubf(unsigned short h) {
    return __uint_as_float(((unsigned)h) << 16);
}
__device__ inline uint4 pack8(const unsigned short* p) {
    uint4 u;
    u.x = (unsigned)p[0] | ((unsigned)p[1] << 16);
    u.y = (unsigned)p[2] | ((unsigned)p[3] << 16);
    u.z = (unsigned)p[4] | ((unsigned)p[5] << 16);
    u.w = (unsigned)p[6] | ((unsigned)p[7] << 16);
    return u;
}
// pfch is tiled: offset(c, n) = (n>>5)*4096 + c*32 + (n&31)
__device__ inline size_t pfchoff(int c, int n) {
    return ((size_t)(n >> 5) << 12) + (c << 5) + (n & 31);
}

// ---------------------------------------------------------------------------
// Merge 7/5/3 kernels into one 7x7; emit bf16 hi/lo in A-FRAGMENT LANE ORDER.
// ---------------------------------------------------------------------------
__global__ void wmerge_kernel(const float* __restrict__ k7, const float* __restrict__ k5,
                              const float* __restrict__ k3, int Cin, int nch,
                              unsigned short* __restrict__ wTh, unsigned short* __restrict__ wTl)
{
    int idx = blockIdx.x * 256 + threadIdx.x;
    int total = 49 * nch * 1024;
    if (idx >= total) return;
    int e = idx & 7;
    int lane = (idx >> 3) & 63;
    int octile = (idx >> 9) & 1;
    int chunk = (idx >> 10) % nch;
    int tap = idx / (nch << 10);
    int oc = octile * 16 + (lane & 15);
    int ci = chunk * 32 + (lane >> 4) * 8 + e;
    int ky = tap / 7, kx = tap % 7;
    float v = 0.f;
    if (ci < Cin) {
        v = k7[(oc * Cin + ci) * 49 + tap];
        if (ky >= 1 && ky <= 5 && kx >= 1 && kx <= 5)
            v += k5[(oc * Cin + ci) * 25 + (ky - 1) * 5 + (kx - 1)];
        if (ky >= 2 && ky <= 4 && kx >= 2 && kx <= 4)
            v += k3[(oc * Cin + ci) * 9 + (ky - 2) * 3 + (kx - 2)];
    }
    unsigned short h = f2bf(v);
    wTh[idx] = h;
    wTl[idx] = f2bf(v - ubf(h));
}

// ---------------------------------------------------------------------------
// x [103][HW] fp32 -> xT [n][128] bf16 hi/lo and pfch (tiled) rows 0..102
// ---------------------------------------------------------------------------
__global__ __launch_bounds__(256) void transpose_kernel(
    const float* __restrict__ x,
    unsigned short* __restrict__ xTh, unsigned short* __restrict__ xTl,
    unsigned short* __restrict__ pfch)
{
    __shared__ float buf[64 * 105];
    int t = threadIdx.x;
    int px0 = blockIdx.x * 64;
    for (int i = t; i < 103 * 64; i += 256) {
        int c = i >> 6, lane = i & 63;
        int n = px0 + lane;
        float v = x[(size_t)c * HW + n];
        buf[lane * 105 + c] = v;
        pfch[pfchoff(c, n)] = f2bf(v);
    }
    __syncthreads();
    int px = t >> 2, seg = t & 3;
    unsigned short h[32], l[32];
#pragma unroll
    for (int j = 0; j < 32; ++j) {
        int c = seg * 32 + j;
        float v = (c < 103) ? buf[px * 105 + c] : 0.f;
        h[j] = f2bf(v);
        l[j] = f2bf(v - ubf(h[j]));
    }
    size_t base = (size_t)(px0 + px) * 128 + seg * 32;
#pragma unroll
    for (int k = 0; k < 4; ++k) {
        *(uint4*)(xTh + base + k * 8) = pack8(h + k * 8);
        *(uint4*)(xTl + base + k * 8) = pack8(l + k * 8);
    }
}

// ---------------------------------------------------------------------------
// Implicit-GEMM 7x7 conv, MFMA 16x16x32 bf16, 3-phase hi/lo.
// 4 rows per wave (16-row block tile). Weights in LDS 3-tap ring.
// Grid (256, 2) with z-split work ranges. XCD-aware tile swizzle.
// ---------------------------------------------------------------------------
__global__ __launch_bounds__(256) void convm_kernel(
    const unsigned short* __restrict__ actH, const unsigned short* __restrict__ actL,
    int Cs,
    const unsigned short* __restrict__ wTh, const unsigned short* __restrict__ wTl,
    int nchw,
    int c0a, int c1a, int t0a, int t1a,
    int c0b, int c1b, int t0b, int t1b,
    float* __restrict__ ypart)
{
    __shared__ __align__(16) unsigned short sH[22 * 704];
    __shared__ __align__(16) unsigned short sL[22 * 704];
    __shared__ __align__(16) unsigned short sW[3 * 2048];
    int t = threadIdx.x;
    int w = t >> 6, l = t & 63;
    int lc = l & 15, lg = l >> 4;
    int bid = blockIdx.x;
    int swz = (bid & 7) * 32 + (bid >> 3);   // bijective: 256 = 8 XCDs x 32
    int bx = swz & 15, byy = swz >> 4;
    int x0 = bx * 16, y0 = byy * 16;
    int z = blockIdx.y;
    int ch0 = z ? c0b : c0a, ch1 = z ? c1b : c1a;
    int tap0 = z ? t0b : t0a, tap1 = z ? t1b : t1a;
    float* yp = ypart + (size_t)z * 32 * HW;

    f32x4 a_hh[2][4], a_lh[2][4], a_hl[2][4];   // [oc-tile][row]
#pragma unroll
    for (int ot = 0; ot < 2; ++ot)
#pragma unroll
        for (int rr = 0; rr < 4; ++rr)
#pragma unroll
            for (int r = 0; r < 4; ++r) {
                a_hh[ot][rr][r] = 0.f; a_lh[ot][rr][r] = 0.f; a_hl[ot][rr][r] = 0.f;
            }

    for (int ch = ch0; ch < ch1; ++ch) {
        int ci0 = ch * 32;
        __syncthreads();                // protect sH/sL from prior reads
        for (int i = t; i < 2 * 22 * 88; i += 256) {
            int pl = (i >= 22 * 88) ? 1 : 0;
            int j = pl ? i - 22 * 88 : i;
            int row = j / 88;
            int rem = j - row * 88;
            int px = rem >> 2, q = rem & 3;
            int gy = y0 - 3 + row, gx = x0 - 3 + px;
            uint4 v = {0u, 0u, 0u, 0u};
            if (gy >= 0 && gy < 256 && gx >= 0 && gx < 256) {
                const unsigned short* src = pl ? actL : actH;
                v = *(const uint4*)(src + (size_t)(gy * 256 + gx) * Cs + ci0 + q * 8);
            }
            unsigned short* dst = pl ? sL : sH;
            *(uint4*)(dst + row * 704 + q * 176 + px * 8) = v;
        }

        for (int g = tap0; g < tap1; g += 3) {
            int ge = g + 3; if (ge > tap1) ge = tap1;
            if (g > tap0) __syncthreads();      // protect sW from prior group reads
            for (int i = t; i < (ge - g) * 256; i += 256) {
                int tp = i >> 8, r = i & 255;
                const unsigned short* src = (r < 128) ? wTh : wTl;
                *(uint4*)(sW + tp * 2048 + r * 8) =
                    *(const uint4*)(src + ((size_t)((g + tp) * nchw + ch)) * 1024 + (r & 127) * 8);
            }
            __syncthreads();

            for (int tap = g; tap < ge; ++tap) {
                const unsigned short* wb = sW + (tap - g) * 2048 + l * 8;
                bf16x8 ah0 = *(const bf16x8*)(wb);
                bf16x8 ah1 = *(const bf16x8*)(wb + 512);
                bf16x8 al0 = *(const bf16x8*)(wb + 1024);
                bf16x8 al1 = *(const bf16x8*)(wb + 1536);
                int ky = tap / 7;
                int kx = tap - ky * 7;
#pragma unroll
                for (int rr = 0; rr < 4; ++rr) {
                    int off = (w * 4 + rr + ky) * 704 + lg * 176 + (lc + kx) * 8;
                    bf16x8 xh = *(const bf16x8*)(sH + off);
                    bf16x8 xl = *(const bf16x8*)(sL + off);
                    a_hh[0][rr] = __builtin_amdgcn_mfma_f32_16x16x32_bf16(ah0, xh, a_hh[0][rr], 0, 0, 0);
                    a_hh[1][rr] = __builtin_amdgcn_mfma_f32_16x16x32_bf16(ah1, xh, a_hh[1][rr], 0, 0, 0);
                    a_lh[0][rr] = __builtin_amdgcn_mfma_f32_16x16x32_bf16(al0, xh, a_lh[0][rr], 0, 0, 0);
                    a_lh[1][rr] = __builtin_amdgcn_mfma_f32_16x16x32_bf16(al1, xh, a_lh[1][rr], 0, 0, 0);
                    a_hl[0][rr] = __builtin_amdgcn_mfma_f32_16x16x32_bf16(ah0, xl, a_hl[0][rr], 0, 0, 0);
                    a_hl[1][rr] = __builtin_amdgcn_mfma_f32_16x16x32_bf16(ah1, xl, a_hl[1][rr], 0, 0, 0);
                }
            }
        }
    }

#pragma unroll
    for (int ot = 0; ot < 2; ++ot)
#pragma unroll
        for (int rr = 0; rr < 4; ++rr) {
            int n = (y0 + w * 4 + rr) * 256 + x0 + lc;
#pragma unroll
            for (int r = 0; r < 4; ++r) {
                int oc = ot * 16 + lg * 4 + r;
                yp[(size_t)oc * HW + n] = a_hh[ot][rr][r] + a_lh[ot][rr][r] + a_hl[ot][rr][r];
            }
        }
}

// ---------------------------------------------------------------------------
// Sum 2 partial planes -> ysum, with fused per-channel sum/sumsq stats.
// ---------------------------------------------------------------------------
__global__ __launch_bounds__(256) void reduce2_kernel(
    const float* __restrict__ p0, const float* __restrict__ p1,
    float* __restrict__ y, float* __restrict__ ssum, float* __restrict__ ssq)
{
    int c = blockIdx.x >> 5, seg = blockIdx.x & 31;
    int base = c * HW + seg * 2048 + threadIdx.x * 8;
    float s = 0.f, q = 0.f;
#pragma unroll
    for (int h = 0; h < 2; ++h) {
        int o = base + h * 4;
        float4 a0 = *(const float4*)&p0[o];
        float4 a1 = *(const float4*)&p1[o];
        float4 v;
        v.x = a0.x + a1.x; v.y = a0.y + a1.y;
        v.z = a0.z + a1.z; v.w = a0.w + a1.w;
        *(float4*)&y[o] = v;
        s += v.x + v.y + v.z + v.w;
        q = fmaf(v.x, v.x, q); q = fmaf(v.y, v.y, q);
        q = fmaf(v.z, v.z, q); q = fmaf(v.w, v.w, q);
    }
#pragma unroll
    for (int d = 32; d >= 1; d >>= 1) {
        s += __shfl_down(s, d);
        q += __shfl_down(q, d);
    }
    __shared__ float ls[4], lq[4];
    int w = threadIdx.x >> 6;
    if ((threadIdx.x & 63) == 0) { ls[w] = s; lq[w] = q; }
    __syncthreads();
    if (threadIdx.x == 0) {
        atomicAdd(&ssum[c], ls[0] + ls[1] + ls[2] + ls[3]);
        atomicAdd(&ssq[c], lq[0] + lq[1] + lq[2] + lq[3]);
    }
}

__global__ void bnp_kernel(const float* __restrict__ ssum, const float* __restrict__ ssq,
                           const float* __restrict__ g, const float* __restrict__ beta,
                           float* __restrict__ scl, float* __restrict__ shf)
{
    int c = threadIdx.x;
    float mu  = ssum[c] * (1.f / 65536.f);
    float var = ssq[c] * (1.f / 65536.f) - mu * mu;
    float s = g[c] * rsqrtf(var + 1e-5f);
    scl[c] = s;
    shf[c] = beta[c] - mu * s;
}

// ---------------------------------------------------------------------------
// BN + ReLU + write channel-last bf16 hi/lo
// ---------------------------------------------------------------------------
__global__ __launch_bounds__(256) void bna_kernel(
    const float* __restrict__ yraw, const float* __restrict__ scl, const float* __restrict__ shf,
    unsigned short* __restrict__ aH, unsigned short* __restrict__ aL, int Cs, int slot0)
{
    int t = threadIdx.x;
    int lane = t & 63, cg = t >> 6;
    int px = blockIdx.x * 64 + lane;
    unsigned short h[8], l[8];
#pragma unroll
    for (int j = 0; j < 8; ++j) {
        int c = cg * 8 + j;
        float v = fmaxf(yraw[(size_t)c * HW + px] * scl[c] + shf[c], 0.f);
        h[j] = f2bf(v);
        l[j] = f2bf(v - ubf(h[j]));
    }
    *(uint4*)(aH + (size_t)px * Cs + slot0 + cg * 8) = pack8(h);
    *(uint4*)(aL + (size_t)px * Cs + slot0 + cg * 8) = pack8(l);
}

// ---------------------------------------------------------------------------
// 1x1 conv (96->15) + ReLU; writes pf slots 103..127 of xT and pfch (tiled)
// ---------------------------------------------------------------------------
__global__ __launch_bounds__(256) void feat_kernel(
    const unsigned short* __restrict__ a12H, const unsigned short* __restrict__ a12L,
    const unsigned short* __restrict__ a3H, const unsigned short* __restrict__ a3L,
    const float* __restrict__ w, const float* __restrict__ b,
    unsigned short* __restrict__ xTh, unsigned short* __restrict__ xTl,
    unsigned short* __restrict__ pfch)
{
    int n = blockIdx.x * 256 + threadIdx.x;
    float facc[15];
#pragma unroll
    for (int oc = 0; oc < 15; ++oc) facc[oc] = b[oc];

#pragma unroll
    for (int k = 0; k < 12; ++k) {
        uint4 uh, ul;
        if (k < 8) {
            uh = *(const uint4*)(a12H + (size_t)n * 64 + k * 8);
            ul = *(const uint4*)(a12L + (size_t)n * 64 + k * 8);
        } else {
            uh = *(const uint4*)(a3H + (size_t)n * 32 + (k - 8) * 8);
            ul = *(const uint4*)(a3L + (size_t)n * 32 + (k - 8) * 8);
        }
        unsigned hw_[4] = {uh.x, uh.y, uh.z, uh.w};
        unsigned lw_[4] = {ul.x, ul.y, ul.z, ul.w};
#pragma unroll
        for (int j = 0; j < 8; ++j) {
            unsigned short hh = (unsigned short)(hw_[j >> 1] >> ((j & 1) * 16));
            unsigned short ll = (unsigned short)(lw_[j >> 1] >> ((j & 1) * 16));
            float av = ubf(hh) + ubf(ll);
#pragma unroll
            for (int oc = 0; oc < 15; ++oc)
                facc[oc] = fmaf(av, w[oc * 96 + k * 8 + j], facc[oc]);
        }
    }
    unsigned short fh[16], fl[16];
#pragma unroll
    for (int oc = 0; oc < 15; ++oc) {
        float v = fmaxf(facc[oc], 0.f);
        fh[oc] = f2bf(v);
        fl[oc] = f2bf(v - ubf(fh[oc]));
    }
    fh[15] = 0; fl[15] = 0;

    size_t base = (size_t)n * 128;
    uint4 h0 = *(const uint4*)(xTh + base + 96);
    uint4 l0 = *(const uint4*)(xTl + base + 96);
    h0.w = (h0.w & 0xFFFFu) | ((unsigned)fh[0] << 16);
    l0.w = (l0.w & 0xFFFFu) | ((unsigned)fl[0] << 16);
    *(uint4*)(xTh + base + 96) = h0;
    *(uint4*)(xTl + base + 96) = l0;
    *(uint4*)(xTh + base + 104) = pack8(fh + 1);
    *(uint4*)(xTl + base + 104) = pack8(fl + 1);
    unsigned short t2h[8], t2l[8];
#pragma unroll
    for (int j = 0; j < 8; ++j) {
        t2h[j] = (j < 6) ? fh[9 + j] : (unsigned short)0;
        t2l[j] = (j < 6) ? fl[9 + j] : (unsigned short)0;
    }
    *(uint4*)(xTh + base + 112) = pack8(t2h);
    *(uint4*)(xTl + base + 112) = pack8(t2l);
    unsigned short t3h[8] = {0, 0, 0, 0, 0, 0, 0, 0x3F80};
    unsigned short t3l[8] = {0, 0, 0, 0, 0, 0, 0, 0};
    *(uint4*)(xTh + base + 120) = pack8(t3h);
    *(uint4*)(xTl + base + 120) = pack8(t3l);

#pragma unroll
    for (int k2 = 0; k2 < 15; ++k2)
        pfch[pfchoff(103 + k2, n)] = fh[k2];
    pfch[pfchoff(118, n)] = 0x3F80;
#pragma unroll
    for (int c = 119; c < 128; ++c)
        pfch[pfchoff(c, n)] = 0;
}

// ---------------------------------------------------------------------------
// c0: per-superpixel channel sums -> cn_fin[s][128]
// ---------------------------------------------------------------------------
__global__ __launch_bounds__(256) void c0_kernel(
    const unsigned short* __restrict__ pfTh, const unsigned short* __restrict__ pfTl,
    float* __restrict__ cn_fin)
{
    int s = blockIdx.x;
    int sy = s >> 4, sx = s & 15;
    int t = threadIdx.x;
    int xx = t >> 4;
    int cs = (t & 15) * 8;

    float acc[8];
#pragma unroll
    for (int j = 0; j < 8; ++j) acc[j] = 0.f;

    for (int yy = 0; yy < 16; ++yy) {
        int n = (sy * 16 + yy) * 256 + sx * 16 + xx;
        u16x8 h = *(const u16x8*)(pfTh + (size_t)n * 128 + cs);
        u16x8 l = *(const u16x8*)(pfTl + (size_t)n * 128 + cs);
#pragma unroll
        for (int j = 0; j < 8; ++j)
            acc[j] += ubf(h[j]) + ubf(l[j]);
    }
#pragma unroll
    for (int j = 0; j < 8; ++j) {
        acc[j] += __shfl_xor(acc[j], 16);
        acc[j] += __shfl_xor(acc[j], 32);
    }
    __shared__ float red[4][128];
    int w = t >> 6;
    if ((t & 63) < 16) {
#pragma unroll
        for (int j = 0; j < 8; ++j)
            red[w][(t & 15) * 8 + j] = acc[j];
    }
    __syncthreads();
    if (t < 128)
        cn_fin[s * 128 + t] = red[0][t] + red[1][t] + red[2][t] + red[3][t];
}

// ---------------------------------------------------------------------------
// prep (init only): centroids from c0 sums -> chiT/cloT; slot 127 = -0.5|c|^2
// ---------------------------------------------------------------------------
__global__ __launch_bounds__(128) void prep_kernel(
    const float* __restrict__ src,
    unsigned short* __restrict__ chiT, unsigned short* __restrict__ cloT,
    float scale0)
{
    int s = blockIdx.x, c = threadIdx.x;
    float v = src[s * 128 + c];
    v = (c < 118) ? v * scale0 : 0.f;
    float a = v * v;
#pragma unroll
    for (int d = 1; d < 64; d <<= 1) a += __shfl_xor(a, d);
    __shared__ float red[2];
    if ((c & 63) == 0) red[c >> 6] = a;
    __syncthreads();
    float tot = red[0] + red[1];
    unsigned short h, lo;
    if (c == 127) {
        float m2 = -0.5f * tot;
        h = f2bf(m2);
        lo = f2bf(m2 - ubf(h));
    } else {
        h = f2bf(v);
        lo = f2bf(v - ubf(h));
    }
    chiT[s * 128 + c] = h;
    cloT[s * 128 + c] = lo;
}

// ---------------------------------------------------------------------------
// redprep: sum 256 cn_part slices for one superpixel + prep in one kernel.
// Grid 256 (s). Block 128 (c). Coalesced 512B reads per k-slice.
// ---------------------------------------------------------------------------
__global__ __launch_bounds__(128) void redprep_kernel(
    const float* __restrict__ cn_part,
    unsigned short* __restrict__ chiT, unsigned short* __restrict__ cloT)
{
    int s = blockIdx.x, c = threadIdx.x;
    float a = 0.f;
    for (int k = 0; k < 256; ++k)
        a += cn_part[(size_t)k * 32768 + s * 128 + c];
    __shared__ float sums[128];
    sums[c] = a;
    __syncthreads();
    float inv = 1.f / (sums[118] + 1e-8f);
    float v = (c < 118) ? a * inv : 0.f;
    float q = v * v;
#pragma unroll
    for (int d = 1; d < 64; d <<= 1) q += __shfl_xor(q, d);
    __shared__ float red[2];
    if ((c & 63) == 0) red[c >> 6] = q;
    __syncthreads();
    float tot = red[0] + red[1];
    unsigned short h, lo;
    if (c == 127) {
        float m2 = -0.5f * tot;
        h = f2bf(m2);
        lo = f2bf(m2 - ubf(h));
    } else {
        h = f2bf(v);
        lo = f2bf(v - ubf(h));
    }
    chiT[s * 128 + c] = h;
    cloT[s * 128 + c] = lo;
}

// ---------------------------------------------------------------------------
// FUSED dist+cn. Block 512 thr = 8 waves = 256 px. Grid 256 (1 block/CU).
// Phase 1: centroid staging in 4 rounds (32 KB, XOR-swizzled); B preloaded.
// Phase 2/3: 4 quarters of 64 s-rows; sQ quarter = 64s x 256px = 32 KB;
// phase-3 pfch B-frags hoisted to registers (pb[8], reused all quarters);
// plain stores to cn_part[block] (32 MB total, half of R13).
// final_mode: write fp32 Q to qf, skip phases 2/3.
// ---------------------------------------------------------------------------
__global__ __launch_bounds__(512) void distcn_kernel(
    const unsigned short* __restrict__ chiT, const unsigned short* __restrict__ cloT,
    const unsigned short* __restrict__ pfTh, const unsigned short* __restrict__ pfTl,
    const unsigned short* __restrict__ pfch,
    float* __restrict__ cn_part, float* __restrict__ qf, int final_mode)
{
    __shared__ __align__(16) unsigned short sA[16384];  // 32 KB: A-stage / sQ-quarter
    unsigned short* sQ = sA;
    int t = threadIdx.x;
    int w = t >> 6, l = t & 63;
    int lc = l & 15, lg = l >> 4;
    int nblk = blockIdx.x * 256;
    int n0 = nblk + w * 32;

    // preload all B fragments (each xT element read exactly once)
    bf16x8 bh[4][2], bl[4][2];
#pragma unroll
    for (int ks = 0; ks < 4; ++ks) {
        int kb = ks * 32 + 8 * lg;
        bh[ks][0] = *(const bf16x8*)(pfTh + (size_t)(n0 + lc) * 128 + kb);
        bh[ks][1] = *(const bf16x8*)(pfTh + (size_t)(n0 + 16 + lc) * 128 + kb);
        bl[ks][0] = *(const bf16x8*)(pfTl + (size_t)(n0 + lc) * 128 + kb);
        bl[ks][1] = *(const bf16x8*)(pfTl + (size_t)(n0 + 16 + lc) * 128 + kb);
    }

    f32x4 acc[16][2];
#pragma unroll
    for (int i = 0; i < 16; ++i)
#pragma unroll
        for (int g = 0; g < 2; ++g)
#pragma unroll
            for (int j = 0; j < 4; ++j) acc[i][g][j] = 0.f;

#pragma unroll
    for (int ro = 0; ro < 4; ++ro) {
        __syncthreads();
        // stage s-rows [ro*64, ro*64+64): plane0 = chiT, plane1 = cloT (16 KB each)
        for (int i = t; i < 2048; i += 512) {
            int plane = i >> 10;
            int ii = i & 1023;
            int sl = ii >> 4;
            int j = ii & 15;
            const unsigned short* src = plane ? cloT : chiT;
            uint4 v = *(const uint4*)(src + (((size_t)(ro * 64 + sl)) << 7) + j * 8);
            int ds = ((sl << 7) + j * 8) ^ ((sl & 7) << 3);
            *(uint4*)(sA + plane * 8192 + ds) = v;
        }
        __syncthreads();

#pragma unroll
        for (int s4 = 0; s4 < 4; ++s4) {
            const int st = ro * 4 + s4;
#pragma unroll
            for (int ks = 0; ks < 4; ++ks) {
                int e0 = (((s4 * 16 + lc) << 7) + ks * 32 + lg * 8) ^ ((lc & 7) << 3);
                bf16x8 ah = *(const bf16x8*)(sA + e0);
                bf16x8 al = *(const bf16x8*)(sA + 8192 + e0);
                acc[st][0] = __builtin_amdgcn_mfma_f32_16x16x32_bf16(ah, bh[ks][0], acc[st][0], 0, 0, 0);
                acc[st][0] = __builtin_amdgcn_mfma_f32_16x16x32_bf16(al, bh[ks][0], acc[st][0], 0, 0, 0);
                acc[st][0] = __builtin_amdgcn_mfma_f32_16x16x32_bf16(ah, bl[ks][0], acc[st][0], 0, 0, 0);
                acc[st][1] = __builtin_amdgcn_mfma_f32_16x16x32_bf16(ah, bh[ks][1], acc[st][1], 0, 0, 0);
                acc[st][1] = __builtin_amdgcn_mfma_f32_16x16x32_bf16(al, bh[ks][1], acc[st][1], 0, 0, 0);
                acc[st][1] = __builtin_amdgcn_mfma_f32_16x16x32_bf16(ah, bl[ks][1], acc[st][1], 0, 0, 0);
            }
        }
    }

    float m0 = -1e30f, m1 = -1e30f;
#pragma unroll
    for (int st = 0; st < 16; ++st)
#pragma unroll
        for (int r = 0; r < 4; ++r) {
            m0 = fmaxf(m0, acc[st][0][r]);
            m1 = fmaxf(m1, acc[st][1][r]);
        }
    m0 = fmaxf(m0, __shfl_xor(m0, 16)); m0 = fmaxf(m0, __shfl_xor(m0, 32));
    m1 = fmaxf(m1, __shfl_xor(m1, 16)); m1 = fmaxf(m1, __shfl_xor(m1, 32));

    float s0 = 0.f, s1 = 0.f;
#pragma unroll
    for (int st = 0; st < 16; ++st)
#pragma unroll
        for (int r = 0; r < 4; ++r) {
            float e0 = __expf(2.f * (acc[st][0][r] - m0));
            float e1 = __expf(2.f * (acc[st][1][r] - m1));
            acc[st][0][r] = e0; acc[st][1][r] = e1;
            s0 += e0; s1 += e1;
        }
    s0 += __shfl_xor(s0, 16); s0 += __shfl_xor(s0, 32);
    s1 += __shfl_xor(s1, 16); s1 += __shfl_xor(s1, 32);
    float i0 = 1.f / s0, i1 = 1.f / s1;

    if (final_mode) {
        int nA = n0 + lc, nB = n0 + 16 + lc;
#pragma unroll
        for (int st = 0; st < 16; ++st)
#pragma unroll
            for (int r = 0; r < 4; ++r) {
                int s = st * 16 + lg * 4 + r;
                qf[(size_t)s * HW + nA] = acc[st][0][r] * i0;
                qf[(size_t)s * HW + nB] = acc[st][1][r] * i1;
            }
        return;
    }

    // hoist phase-3 B fragments: wave w covers c in [w*16, w*16+16)
    bf16x8 pb[8];
#pragma unroll
    for (int kc = 0; kc < 8; ++kc)
        pb[kc] = *(const bf16x8*)(pfch + (((size_t)((nblk >> 5) + kc)) << 12)
                                  + (w * 16 + lc) * 32 + lg * 8);

    // phases 2/3 in four s-quarters (sQ quarter = 64 s x 256 px bf16 = 32 KB)
#pragma unroll
    for (int h = 0; h < 4; ++h) {
        __syncthreads();    // previous sA contents (stage or sQ-quarter) dead
#pragma unroll
        for (int s4 = 0; s4 < 4; ++s4) {
            const int st = h * 4 + s4;
#pragma unroll
            for (int g = 0; g < 2; ++g) {
                float iv = g ? i1 : i0;
#pragma unroll
                for (int r = 0; r < 4; ++r) {
                    int idx = ((s4 * 8 + w) * 64 + (g * 2 + (lc >> 3)) * 16 + lg * 4 + r) * 8 + (lc & 7);
                    sQ[idx] = f2bf(acc[st][g][r] * iv);
                }
            }
        }
        __syncthreads();

        f32x4 a2[4];
#pragma unroll
        for (int i = 0; i < 4; ++i)
#pragma unroll
            for (int j = 0; j < 4; ++j) a2[i][j] = 0.f;

#pragma unroll
        for (int kc = 0; kc < 8; ++kc) {
#pragma unroll
            for (int s4 = 0; s4 < 4; ++s4) {
                bf16x8 afr = *(const bf16x8*)(sQ + ((size_t)(s4 * 8 + kc) * 64 + l) * 8);
                a2[s4] = __builtin_amdgcn_mfma_f32_16x16x32_bf16(afr, pb[kc], a2[s4], 0, 0, 0);
            }
        }

        float* out = cn_part + (size_t)blockIdx.x * 32768;
#pragma unroll
        for (int s4 = 0; s4 < 4; ++s4)
#pragma unroll
            for (int r = 0; r < 4; ++r) {
                int s = (h * 4 + s4) * 16 + lg * 4 + r;
                int c = w * 16 + lc;
                out[s * 128 + c] = a2[s4][r];
            }
    }
}

// ---------------------------------------------------------------------------
extern "C" void kernel_launch(void* const* d_in, const int* in_sizes, int n_in,
                              void* d_out, int out_size, void* d_ws, size_t ws_size,
                              hipStream_t stream)
{
    const float* x     = (const float*)d_in[0];
    const float* s1k7  = (const float*)d_in[1];
    const float* s1k5  = (const float*)d_in[2];
    const float* s1k3  = (const float*)d_in[3];
    const float* s1g   = (const float*)d_in[5];
    const float* s1be  = (const float*)d_in[6];
    const float* s2k7  = (const float*)d_in[7];
    const float* s2k5  = (const float*)d_in[8];
    const float* s2k3  = (const float*)d_in[9];
    const float* s2g   = (const float*)d_in[11];
    const float* s2be  = (const float*)d_in[12];
    const float* s3k7  = (const float*)d_in[13];
    const float* s3k5  = (const float*)d_in[14];
    const float* s3k3  = (const float*)d_in[15];
    const float* s3g   = (const float*)d_in[17];
    const float* s3be  = (const float*)d_in[18];
    const float* outw  = (const float*)d_in[19];
    const float* outb  = (const float*)d_in[20];

    float* ws = (float*)d_ws;
    size_t off = 0;
    unsigned short* wT1h = (unsigned short*)(ws + off); off += 100352;
    unsigned short* wT1l = (unsigned short*)(ws + off); off += 100352;
    unsigned short* wT2h = (unsigned short*)(ws + off); off += 25088;
    unsigned short* wT2l = (unsigned short*)(ws + off); off += 25088;
    unsigned short* wT3h = (unsigned short*)(ws + off); off += 50176;
    unsigned short* wT3l = (unsigned short*)(ws + off); off += 50176;
    float* stats = ws + off; off += 192;
    float* bn    = ws + off; off += 192;
    float* cn_fin= ws + off; off += 32768;
    unsigned short* chiT = (unsigned short*)(ws + off); off += 16384;
    unsigned short* cloT = (unsigned short*)(ws + off); off += 16384;
    unsigned short* xTh  = (unsigned short*)(ws + off); off += 4194304;
    unsigned short* xTl  = (unsigned short*)(ws + off); off += 4194304;
    unsigned short* pfch = (unsigned short*)(ws + off); off += 4194304;
    unsigned short* a12H = (unsigned short*)(ws + off); off += 2097152;
    unsigned short* a12L = (unsigned short*)(ws + off); off += 2097152;

    // d_out scratch timeline:
    //   p0 @0, p1 @8MB, ysum @16MB   (conv stages; dead before iterations)
    //   a3H/L @32MB, 8MB             (stage-3 bna -> feat; dead after)
    //   cn_part @0, 32MB             (iterations: 256 x 32768 f32 partials)
    //   qf @0, 64MB                  (final distcn overwrites everything)
    char* ob = (char*)d_out;
    float* p0   = (float*)ob;
    float* p1   = (float*)(ob + (size_t)8 * 1024 * 1024);
    float* ysum = (float*)(ob + (size_t)16 * 1024 * 1024);
    float* cn_part = (float*)ob;
    float* qf = (float*)ob;
    unsigned short* a3H = (unsigned short*)(ob + (size_t)32 * 1024 * 1024);
    unsigned short* a3L = a3H + (size_t)HW * 32;

    hipMemsetAsync(stats, 0, 192 * sizeof(float), stream);
    wmerge_kernel<<<(49 * 4 * 1024 + 255) / 256, 256, 0, stream>>>(s1k7, s1k5, s1k3, 103, 4, wT1h, wT1l);
    wmerge_kernel<<<(49 * 1 * 1024 + 255) / 256, 256, 0, stream>>>(s2k7, s2k5, s2k3, 32, 1, wT2h, wT2l);
    wmerge_kernel<<<(49 * 2 * 1024 + 255) / 256, 256, 0, stream>>>(s3k7, s3k5, s3k3, 64, 2, wT3h, wT3l);

    transpose_kernel<<<1024, 256, 0, stream>>>(x, xTh, xTl, pfch);

    convm_kernel<<<dim3(256, 2), 256, 0, stream>>>(xTh, xTl, 128, wT1h, wT1l, 4,
                                                   0, 2, 0, 49, 2, 4, 0, 49, p0);
    reduce2_kernel<<<1024, 256, 0, stream>>>(p0, p1, ysum, stats + 0, stats + 32);
    bnp_kernel<<<1, 32, 0, stream>>>(stats + 0, stats + 32, s1g, s1be, bn + 0, bn + 32);
    bna_kernel<<<1024, 256, 0, stream>>>(ysum, bn + 0, bn + 32, a12H, a12L, 64, 0);

    convm_kernel<<<dim3(256, 2), 256, 0, stream>>>(a12H, a12L, 64, wT2h, wT2l, 1,
                                                   0, 1, 0, 25, 0, 1, 25, 49, p0);
    reduce2_kernel<<<1024, 256, 0, stream>>>(p0, p1, ysum, stats + 64, stats + 96);
    bnp_kernel<<<1, 32, 0, stream>>>(stats + 64, stats + 96, s2g, s2be, bn + 64, bn + 96);
    bna_kernel<<<1024, 256, 0, stream>>>(ysum, bn + 64, bn + 96, a12H, a12L, 64, 32);

    convm_kernel<<<dim3(256, 2), 256, 0, stream>>>(a12H, a12L, 64, wT3h, wT3l, 2,
                                                   0, 1, 0, 49, 1, 2, 0, 49, p0);
    reduce2_kernel<<<1024, 256, 0, stream>>>(p0, p1, ysum, stats + 128, stats + 160);
    bnp_kernel<<<1, 32, 0, stream>>>(stats + 128, stats + 160, s3g, s3be, bn + 128, bn + 160);
    bna_kernel<<<1024, 256, 0, stream>>>(ysum, bn + 128, bn + 160, a3H, a3L, 32, 0);

    feat_kernel<<<256, 256, 0, stream>>>(a12H, a12L, a3H, a3L, outw, outb, xTh, xTl, pfch);
    c0_kernel<<<256, 256, 0, stream>>>(xTh, xTl, cn_fin);
    prep_kernel<<<256, 128, 0, stream>>>(cn_fin, chiT, cloT, 1.f / 256.f);

    for (int it = 0; it < 5; ++it) {
        distcn_kernel<<<256, 512, 0, stream>>>(chiT, cloT, xTh, xTl, pfch, cn_part, qf, 0);
        redprep_kernel<<<256, 128, 0, stream>>>(cn_part, chiT, cloT);
    }
    distcn_kernel<<<256, 512, 0, stream>>>(chiT, cloT, xTh, xTl, pfch, cn_part, qf, 1);
}

// Round 15
// 501.748 us; speedup vs baseline: 1.3495x; 1.0220x over previous
//
#include <hip/hip_runtime.h>

#define HW 65536

typedef short bf16x8 __attribute__((ext_vector_type(8)));
typedef float f32x4 __attribute__((ext_vector_type(4)));
typedef unsigned short u16x8 __attribute__((ext_vector_type(8)));

__device__ inline unsigned short f2bf(float v) {
    unsigned u = __float_as_uint(v);
    unsigned r = (u + 0x7FFF + ((u >> 16) & 1)) >> 16;
    return (unsigned short)r;
}
__device__ inline float ubf(unsigned short h) {
    return __uint_as_float(((unsigned)h) << 16);
}
__device__ inline uint4 pack8(const unsigned short* p) {
    uint4 u;
    u.x = (unsigned)p[0] | ((unsigned)p[1] << 16);
    u.y = (unsigned)p[2] | ((unsigned)p[3] << 16);
    u.z = (unsigned)p[4] | ((unsigned)p[5] << 16);
    u.w = (unsigned)p[6] | ((unsigned)p[7] << 16);
    return u;
}
// pfch is tiled: offset(c, n) = (n>>5)*4096 + c*32 + (n&31)
__device__ inline size_t pfchoff(int c, int n) {
    return ((size_t)(n >> 5) << 12) + (c << 5) + (n & 31);
}

// ---------------------------------------------------------------------------
// Merge 7/5/3 kernels into one 7x7; emit bf16 hi/lo in A-FRAGMENT LANE ORDER.
// ---------------------------------------------------------------------------
__global__ void wmerge_kernel(const float* __restrict__ k7, const float* __restrict__ k5,
                              const float* __restrict__ k3, int Cin, int nch,
                              unsigned short* __restrict__ wTh, unsigned short* __restrict__ wTl)
{
    int idx = blockIdx.x * 256 + threadIdx.x;
    int total = 49 * nch * 1024;
    if (idx >= total) return;
    int e = idx & 7;
    int lane = (idx >> 3) & 63;
    int octile = (idx >> 9) & 1;
    int chunk = (idx >> 10) % nch;
    int tap = idx / (nch << 10);
    int oc = octile * 16 + (lane & 15);
    int ci = chunk * 32 + (lane >> 4) * 8 + e;
    int ky = tap / 7, kx = tap % 7;
    float v = 0.f;
    if (ci < Cin) {
        v = k7[(oc * Cin + ci) * 49 + tap];
        if (ky >= 1 && ky <= 5 && kx >= 1 && kx <= 5)
            v += k5[(oc * Cin + ci) * 25 + (ky - 1) * 5 + (kx - 1)];
        if (ky >= 2 && ky <= 4 && kx >= 2 && kx <= 4)
            v += k3[(oc * Cin + ci) * 9 + (ky - 2) * 3 + (kx - 2)];
    }
    unsigned short h = f2bf(v);
    wTh[idx] = h;
    wTl[idx] = f2bf(v - ubf(h));
}

// ---------------------------------------------------------------------------
// x [103][HW] fp32 -> xT [n][128] bf16 hi/lo and pfch (tiled) rows 0..102
// ---------------------------------------------------------------------------
__global__ __launch_bounds__(256) void transpose_kernel(
    const float* __restrict__ x,
    unsigned short* __restrict__ xTh, unsigned short* __restrict__ xTl,
    unsigned short* __restrict__ pfch)
{
    __shared__ float buf[64 * 105];
    int t = threadIdx.x;
    int px0 = blockIdx.x * 64;
    for (int i = t; i < 103 * 64; i += 256) {
        int c = i >> 6, lane = i & 63;
        int n = px0 + lane;
        float v = x[(size_t)c * HW + n];
        buf[lane * 105 + c] = v;
        pfch[pfchoff(c, n)] = f2bf(v);
    }
    __syncthreads();
    int px = t >> 2, seg = t & 3;
    unsigned short h[32], l[32];
#pragma unroll
    for (int j = 0; j < 32; ++j) {
        int c = seg * 32 + j;
        float v = (c < 103) ? buf[px * 105 + c] : 0.f;
        h[j] = f2bf(v);
        l[j] = f2bf(v - ubf(h[j]));
    }
    size_t base = (size_t)(px0 + px) * 128 + seg * 32;
#pragma unroll
    for (int k = 0; k < 4; ++k) {
        *(uint4*)(xTh + base + k * 8) = pack8(h + k * 8);
        *(uint4*)(xTl + base + k * 8) = pack8(l + k * 8);
    }
}

// ---------------------------------------------------------------------------
// Implicit-GEMM 7x7 conv, MFMA 16x16x32 bf16, 3-phase hi/lo.
// 4 rows per wave (16-row block tile). Weights in LDS 3-tap ring.
// Grid (256, 2) with z-split work ranges. XCD-aware tile swizzle.
// ---------------------------------------------------------------------------
__global__ __launch_bounds__(256) void convm_kernel(
    const unsigned short* __restrict__ actH, const unsigned short* __restrict__ actL,
    int Cs,
    const unsigned short* __restrict__ wTh, const unsigned short* __restrict__ wTl,
    int nchw,
    int c0a, int c1a, int t0a, int t1a,
    int c0b, int c1b, int t0b, int t1b,
    float* __restrict__ ypart)
{
    __shared__ __align__(16) unsigned short sH[22 * 704];
    __shared__ __align__(16) unsigned short sL[22 * 704];
    __shared__ __align__(16) unsigned short sW[3 * 2048];
    int t = threadIdx.x;
    int w = t >> 6, l = t & 63;
    int lc = l & 15, lg = l >> 4;
    int bid = blockIdx.x;
    int swz = (bid & 7) * 32 + (bid >> 3);   // bijective: 256 = 8 XCDs x 32
    int bx = swz & 15, byy = swz >> 4;
    int x0 = bx * 16, y0 = byy * 16;
    int z = blockIdx.y;
    int ch0 = z ? c0b : c0a, ch1 = z ? c1b : c1a;
    int tap0 = z ? t0b : t0a, tap1 = z ? t1b : t1a;
    float* yp = ypart + (size_t)z * 32 * HW;

    f32x4 a_hh[2][4], a_lh[2][4], a_hl[2][4];   // [oc-tile][row]
#pragma unroll
    for (int ot = 0; ot < 2; ++ot)
#pragma unroll
        for (int rr = 0; rr < 4; ++rr)
#pragma unroll
            for (int r = 0; r < 4; ++r) {
                a_hh[ot][rr][r] = 0.f; a_lh[ot][rr][r] = 0.f; a_hl[ot][rr][r] = 0.f;
            }

    for (int ch = ch0; ch < ch1; ++ch) {
        int ci0 = ch * 32;
        __syncthreads();                // protect sH/sL from prior reads
        for (int i = t; i < 2 * 22 * 88; i += 256) {
            int pl = (i >= 22 * 88) ? 1 : 0;
            int j = pl ? i - 22 * 88 : i;
            int row = j / 88;
            int rem = j - row * 88;
            int px = rem >> 2, q = rem & 3;
            int gy = y0 - 3 + row, gx = x0 - 3 + px;
            uint4 v = {0u, 0u, 0u, 0u};
            if (gy >= 0 && gy < 256 && gx >= 0 && gx < 256) {
                const unsigned short* src = pl ? actL : actH;
                v = *(const uint4*)(src + (size_t)(gy * 256 + gx) * Cs + ci0 + q * 8);
            }
            unsigned short* dst = pl ? sL : sH;
            *(uint4*)(dst + row * 704 + q * 176 + px * 8) = v;
        }

        for (int g = tap0; g < tap1; g += 3) {
            int ge = g + 3; if (ge > tap1) ge = tap1;
            if (g > tap0) __syncthreads();      // protect sW from prior group reads
            for (int i = t; i < (ge - g) * 256; i += 256) {
                int tp = i >> 8, r = i & 255;
                const unsigned short* src = (r < 128) ? wTh : wTl;
                *(uint4*)(sW + tp * 2048 + r * 8) =
                    *(const uint4*)(src + ((size_t)((g + tp) * nchw + ch)) * 1024 + (r & 127) * 8);
            }
            __syncthreads();

            for (int tap = g; tap < ge; ++tap) {
                const unsigned short* wb = sW + (tap - g) * 2048 + l * 8;
                bf16x8 ah0 = *(const bf16x8*)(wb);
                bf16x8 ah1 = *(const bf16x8*)(wb + 512);
                bf16x8 al0 = *(const bf16x8*)(wb + 1024);
                bf16x8 al1 = *(const bf16x8*)(wb + 1536);
                int ky = tap / 7;
                int kx = tap - ky * 7;
#pragma unroll
                for (int rr = 0; rr < 4; ++rr) {
                    int off = (w * 4 + rr + ky) * 704 + lg * 176 + (lc + kx) * 8;
                    bf16x8 xh = *(const bf16x8*)(sH + off);
                    bf16x8 xl = *(const bf16x8*)(sL + off);
                    a_hh[0][rr] = __builtin_amdgcn_mfma_f32_16x16x32_bf16(ah0, xh, a_hh[0][rr], 0, 0, 0);
                    a_hh[1][rr] = __builtin_amdgcn_mfma_f32_16x16x32_bf16(ah1, xh, a_hh[1][rr], 0, 0, 0);
                    a_lh[0][rr] = __builtin_amdgcn_mfma_f32_16x16x32_bf16(al0, xh, a_lh[0][rr], 0, 0, 0);
                    a_lh[1][rr] = __builtin_amdgcn_mfma_f32_16x16x32_bf16(al1, xh, a_lh[1][rr], 0, 0, 0);
                    a_hl[0][rr] = __builtin_amdgcn_mfma_f32_16x16x32_bf16(ah0, xl, a_hl[0][rr], 0, 0, 0);
                    a_hl[1][rr] = __builtin_amdgcn_mfma_f32_16x16x32_bf16(ah1, xl, a_hl[1][rr], 0, 0, 0);
                }
            }
        }
    }

#pragma unroll
    for (int ot = 0; ot < 2; ++ot)
#pragma unroll
        for (int rr = 0; rr < 4; ++rr) {
            int n = (y0 + w * 4 + rr) * 256 + x0 + lc;
#pragma unroll
            for (int r = 0; r < 4; ++r) {
                int oc = ot * 16 + lg * 4 + r;
                yp[(size_t)oc * HW + n] = a_hh[ot][rr][r] + a_lh[ot][rr][r] + a_hl[ot][rr][r];
            }
        }
}

// ---------------------------------------------------------------------------
// Sum 2 partial planes -> ysum, with fused per-channel sum/sumsq stats.
// ---------------------------------------------------------------------------
__global__ __launch_bounds__(256) void reduce2_kernel(
    const float* __restrict__ p0, const float* __restrict__ p1,
    float* __restrict__ y, float* __restrict__ ssum, float* __restrict__ ssq)
{
    int c = blockIdx.x >> 5, seg = blockIdx.x & 31;
    int base = c * HW + seg * 2048 + threadIdx.x * 8;
    float s = 0.f, q = 0.f;
#pragma unroll
    for (int h = 0; h < 2; ++h) {
        int o = base + h * 4;
        float4 a0 = *(const float4*)&p0[o];
        float4 a1 = *(const float4*)&p1[o];
        float4 v;
        v.x = a0.x + a1.x; v.y = a0.y + a1.y;
        v.z = a0.z + a1.z; v.w = a0.w + a1.w;
        *(float4*)&y[o] = v;
        s += v.x + v.y + v.z + v.w;
        q = fmaf(v.x, v.x, q); q = fmaf(v.y, v.y, q);
        q = fmaf(v.z, v.z, q); q = fmaf(v.w, v.w, q);
    }
#pragma unroll
    for (int d = 32; d >= 1; d >>= 1) {
        s += __shfl_down(s, d);
        q += __shfl_down(q, d);
    }
    __shared__ float ls[4], lq[4];
    int w = threadIdx.x >> 6;
    if ((threadIdx.x & 63) == 0) { ls[w] = s; lq[w] = q; }
    __syncthreads();
    if (threadIdx.x == 0) {
        atomicAdd(&ssum[c], ls[0] + ls[1] + ls[2] + ls[3]);
        atomicAdd(&ssq[c], lq[0] + lq[1] + lq[2] + lq[3]);
    }
}

__global__ void bnp_kernel(const float* __restrict__ ssum, const float* __restrict__ ssq,
                           const float* __restrict__ g, const float* __restrict__ beta,
                           float* __restrict__ scl, float* __restrict__ shf)
{
    int c = threadIdx.x;
    float mu  = ssum[c] * (1.f / 65536.f);
    float var = ssq[c] * (1.f / 65536.f) - mu * mu;
    float s = g[c] * rsqrtf(var + 1e-5f);
    scl[c] = s;
    shf[c] = beta[c] - mu * s;
}

// ---------------------------------------------------------------------------
// BN + ReLU + write channel-last bf16 hi/lo
// ---------------------------------------------------------------------------
__global__ __launch_bounds__(256) void bna_kernel(
    const float* __restrict__ yraw, const float* __restrict__ scl, const float* __restrict__ shf,
    unsigned short* __restrict__ aH, unsigned short* __restrict__ aL, int Cs, int slot0)
{
    int t = threadIdx.x;
    int lane = t & 63, cg = t >> 6;
    int px = blockIdx.x * 64 + lane;
    unsigned short h[8], l[8];
#pragma unroll
    for (int j = 0; j < 8; ++j) {
        int c = cg * 8 + j;
        float v = fmaxf(yraw[(size_t)c * HW + px] * scl[c] + shf[c], 0.f);
        h[j] = f2bf(v);
        l[j] = f2bf(v - ubf(h[j]));
    }
    *(uint4*)(aH + (size_t)px * Cs + slot0 + cg * 8) = pack8(h);
    *(uint4*)(aL + (size_t)px * Cs + slot0 + cg * 8) = pack8(l);
}

// ---------------------------------------------------------------------------
// 1x1 conv (96->15) + ReLU; writes pf slots 103..127 of xT and pfch (tiled)
// ---------------------------------------------------------------------------
__global__ __launch_bounds__(256) void feat_kernel(
    const unsigned short* __restrict__ a12H, const unsigned short* __restrict__ a12L,
    const unsigned short* __restrict__ a3H, const unsigned short* __restrict__ a3L,
    const float* __restrict__ w, const float* __restrict__ b,
    unsigned short* __restrict__ xTh, unsigned short* __restrict__ xTl,
    unsigned short* __restrict__ pfch)
{
    int n = blockIdx.x * 256 + threadIdx.x;
    float facc[15];
#pragma unroll
    for (int oc = 0; oc < 15; ++oc) facc[oc] = b[oc];

#pragma unroll
    for (int k = 0; k < 12; ++k) {
        uint4 uh, ul;
        if (k < 8) {
            uh = *(const uint4*)(a12H + (size_t)n * 64 + k * 8);
            ul = *(const uint4*)(a12L + (size_t)n * 64 + k * 8);
        } else {
            uh = *(const uint4*)(a3H + (size_t)n * 32 + (k - 8) * 8);
            ul = *(const uint4*)(a3L + (size_t)n * 32 + (k - 8) * 8);
        }
        unsigned hw_[4] = {uh.x, uh.y, uh.z, uh.w};
        unsigned lw_[4] = {ul.x, ul.y, ul.z, ul.w};
#pragma unroll
        for (int j = 0; j < 8; ++j) {
            unsigned short hh = (unsigned short)(hw_[j >> 1] >> ((j & 1) * 16));
            unsigned short ll = (unsigned short)(lw_[j >> 1] >> ((j & 1) * 16));
            float av = ubf(hh) + ubf(ll);
#pragma unroll
            for (int oc = 0; oc < 15; ++oc)
                facc[oc] = fmaf(av, w[oc * 96 + k * 8 + j], facc[oc]);
        }
    }
    unsigned short fh[16], fl[16];
#pragma unroll
    for (int oc = 0; oc < 15; ++oc) {
        float v = fmaxf(facc[oc], 0.f);
        fh[oc] = f2bf(v);
        fl[oc] = f2bf(v - ubf(fh[oc]));
    }
    fh[15] = 0; fl[15] = 0;

    size_t base = (size_t)n * 128;
    uint4 h0 = *(const uint4*)(xTh + base + 96);
    uint4 l0 = *(const uint4*)(xTl + base + 96);
    h0.w = (h0.w & 0xFFFFu) | ((unsigned)fh[0] << 16);
    l0.w = (l0.w & 0xFFFFu) | ((unsigned)fl[0] << 16);
    *(uint4*)(xTh + base + 96) = h0;
    *(uint4*)(xTl + base + 96) = l0;
    *(uint4*)(xTh + base + 104) = pack8(fh + 1);
    *(uint4*)(xTl + base + 104) = pack8(fl + 1);
    unsigned short t2h[8], t2l[8];
#pragma unroll
    for (int j = 0; j < 8; ++j) {
        t2h[j] = (j < 6) ? fh[9 + j] : (unsigned short)0;
        t2l[j] = (j < 6) ? fl[9 + j] : (unsigned short)0;
    }
    *(uint4*)(xTh + base + 112) = pack8(t2h);
    *(uint4*)(xTl + base + 112) = pack8(t2l);
    unsigned short t3h[8] = {0, 0, 0, 0, 0, 0, 0, 0x3F80};
    unsigned short t3l[8] = {0, 0, 0, 0, 0, 0, 0, 0};
    *(uint4*)(xTh + base + 120) = pack8(t3h);
    *(uint4*)(xTl + base + 120) = pack8(t3l);

#pragma unroll
    for (int k2 = 0; k2 < 15; ++k2)
        pfch[pfchoff(103 + k2, n)] = fh[k2];
    pfch[pfchoff(118, n)] = 0x3F80;
#pragma unroll
    for (int c = 119; c < 128; ++c)
        pfch[pfchoff(c, n)] = 0;
}

// ---------------------------------------------------------------------------
// c0: per-superpixel channel sums -> cn_fin[s][128]
// ---------------------------------------------------------------------------
__global__ __launch_bounds__(256) void c0_kernel(
    const unsigned short* __restrict__ pfTh, const unsigned short* __restrict__ pfTl,
    float* __restrict__ cn_fin)
{
    int s = blockIdx.x;
    int sy = s >> 4, sx = s & 15;
    int t = threadIdx.x;
    int xx = t >> 4;
    int cs = (t & 15) * 8;

    float acc[8];
#pragma unroll
    for (int j = 0; j < 8; ++j) acc[j] = 0.f;

    for (int yy = 0; yy < 16; ++yy) {
        int n = (sy * 16 + yy) * 256 + sx * 16 + xx;
        u16x8 h = *(const u16x8*)(pfTh + (size_t)n * 128 + cs);
        u16x8 l = *(const u16x8*)(pfTl + (size_t)n * 128 + cs);
#pragma unroll
        for (int j = 0; j < 8; ++j)
            acc[j] += ubf(h[j]) + ubf(l[j]);
    }
#pragma unroll
    for (int j = 0; j < 8; ++j) {
        acc[j] += __shfl_xor(acc[j], 16);
        acc[j] += __shfl_xor(acc[j], 32);
    }
    __shared__ float red[4][128];
    int w = t >> 6;
    if ((t & 63) < 16) {
#pragma unroll
        for (int j = 0; j < 8; ++j)
            red[w][(t & 15) * 8 + j] = acc[j];
    }
    __syncthreads();
    if (t < 128)
        cn_fin[s * 128 + t] = red[0][t] + red[1][t] + red[2][t] + red[3][t];
}

// ---------------------------------------------------------------------------
// prep (init only): centroids from c0 sums -> chiT/cloT; slot 127 = -0.5|c|^2
// ---------------------------------------------------------------------------
__global__ __launch_bounds__(128) void prep_kernel(
    const float* __restrict__ src,
    unsigned short* __restrict__ chiT, unsigned short* __restrict__ cloT,
    float scale0)
{
    int s = blockIdx.x, c = threadIdx.x;
    float v = src[s * 128 + c];
    v = (c < 118) ? v * scale0 : 0.f;
    float a = v * v;
#pragma unroll
    for (int d = 1; d < 64; d <<= 1) a += __shfl_xor(a, d);
    __shared__ float red[2];
    if ((c & 63) == 0) red[c >> 6] = a;
    __syncthreads();
    float tot = red[0] + red[1];
    unsigned short h, lo;
    if (c == 127) {
        float m2 = -0.5f * tot;
        h = f2bf(m2);
        lo = f2bf(m2 - ubf(h));
    } else {
        h = f2bf(v);
        lo = f2bf(v - ubf(h));
    }
    chiT[s * 128 + c] = h;
    cloT[s * 128 + c] = lo;
}

// ---------------------------------------------------------------------------
// redprep: sum 256 cn_part slices for one superpixel + prep in one kernel.
// ---------------------------------------------------------------------------
__global__ __launch_bounds__(128) void redprep_kernel(
    const float* __restrict__ cn_part,
    unsigned short* __restrict__ chiT, unsigned short* __restrict__ cloT)
{
    int s = blockIdx.x, c = threadIdx.x;
    float a = 0.f;
    for (int k = 0; k < 256; ++k)
        a += cn_part[(size_t)k * 32768 + s * 128 + c];
    __shared__ float sums[128];
    sums[c] = a;
    __syncthreads();
    float inv = 1.f / (sums[118] + 1e-8f);
    float v = (c < 118) ? a * inv : 0.f;
    float q = v * v;
#pragma unroll
    for (int d = 1; d < 64; d <<= 1) q += __shfl_xor(q, d);
    __shared__ float red[2];
    if ((c & 63) == 0) red[c >> 6] = q;
    __syncthreads();
    float tot = red[0] + red[1];
    unsigned short h, lo;
    if (c == 127) {
        float m2 = -0.5f * tot;
        h = f2bf(m2);
        lo = f2bf(m2 - ubf(h));
    } else {
        h = f2bf(v);
        lo = f2bf(v - ubf(h));
    }
    chiT[s * 128 + c] = h;
    cloT[s * 128 + c] = lo;
}

// ---------------------------------------------------------------------------
// FUSED dist+cn, double-buffered (T14 async-stage + LDS ping-pong).
// Block 512 thr = 8 waves = 256 px. Grid 256 (1 block/CU). LDS 64 KB.
// Phase 1: stage round ro+1 loads issued BEFORE computing round ro;
//          ds_writes to the other buffer; ONE barrier per round.
// Phase 2/3: sQ quarters ping-pong in the same two buffers: write quarter
//          h+1 while computing quarter h; ONE barrier per quarter.
// final_mode: write fp32 Q to qf, skip phases 2/3.
// ---------------------------------------------------------------------------
__global__ __launch_bounds__(512) void distcn_kernel(
    const unsigned short* __restrict__ chiT, const unsigned short* __restrict__ cloT,
    const unsigned short* __restrict__ pfTh, const unsigned short* __restrict__ pfTl,
    const unsigned short* __restrict__ pfch,
    float* __restrict__ cn_part, float* __restrict__ qf, int final_mode)
{
    __shared__ __align__(16) unsigned short sA0[16384];  // 32 KB buffer 0
    __shared__ __align__(16) unsigned short sA1[16384];  // 32 KB buffer 1
    int t = threadIdx.x;
    int w = t >> 6, l = t & 63;
    int lc = l & 15, lg = l >> 4;
    int nblk = blockIdx.x * 256;
    int n0 = nblk + w * 32;

    // preload all B fragments (each xT element read exactly once)
    bf16x8 bh[4][2], bl[4][2];
#pragma unroll
    for (int ks = 0; ks < 4; ++ks) {
        int kb = ks * 32 + 8 * lg;
        bh[ks][0] = *(const bf16x8*)(pfTh + (size_t)(n0 + lc) * 128 + kb);
        bh[ks][1] = *(const bf16x8*)(pfTh + (size_t)(n0 + 16 + lc) * 128 + kb);
        bl[ks][0] = *(const bf16x8*)(pfTl + (size_t)(n0 + lc) * 128 + kb);
        bl[ks][1] = *(const bf16x8*)(pfTl + (size_t)(n0 + 16 + lc) * 128 + kb);
    }

    // per-thread staging indices (4 chunks of the 32 KB round)
    // i = t + k*512; plane = i>>10; sl = (i&1023)>>4; j = i&15
    int sti[4], std_[4];
#pragma unroll
    for (int k = 0; k < 4; ++k) {
        int i = t + k * 512;
        int plane = i >> 10;
        int ii = i & 1023;
        int sl = ii >> 4;
        int j = ii & 15;
        sti[k] = (plane << 16) | (sl << 4) | j;     // packed
        std_[k] = plane * 8192 + (((sl << 7) + j * 8) ^ ((sl & 7) << 3));
    }

    f32x4 acc[16][2];
#pragma unroll
    for (int i = 0; i < 16; ++i)
#pragma unroll
        for (int g = 0; g < 2; ++g)
#pragma unroll
            for (int j = 0; j < 4; ++j) acc[i][g][j] = 0.f;

    // prologue: stage round 0 into sA0
    {
#pragma unroll
        for (int k = 0; k < 4; ++k) {
            int plane = sti[k] >> 16;
            int sl = (sti[k] >> 4) & 0xFFF;
            int j = sti[k] & 15;
            const unsigned short* src = plane ? cloT : chiT;
            uint4 v = *(const uint4*)(src + (((size_t)sl) << 7) + j * 8);
            unsigned short* dst = sA0;
            *(uint4*)(dst + std_[k]) = v;
        }
    }
    __syncthreads();

#pragma unroll
    for (int ro = 0; ro < 4; ++ro) {
        unsigned short* cur = (ro & 1) ? sA1 : sA0;
        unsigned short* nxt = (ro & 1) ? sA0 : sA1;

        // issue next round's global loads first (hidden under MFMAs)
        uint4 stg[4];
        if (ro < 3) {
#pragma unroll
            for (int k = 0; k < 4; ++k) {
                int plane = sti[k] >> 16;
                int sl = (sti[k] >> 4) & 0xFFF;
                int j = sti[k] & 15;
                const unsigned short* src = plane ? cloT : chiT;
                stg[k] = *(const uint4*)(src + (((size_t)((ro + 1) * 64 + sl)) << 7) + j * 8);
            }
        }

        // compute round ro from cur
#pragma unroll
        for (int s4 = 0; s4 < 4; ++s4) {
            const int st = ro * 4 + s4;
#pragma unroll
            for (int ks = 0; ks < 4; ++ks) {
                int e0 = (((s4 * 16 + lc) << 7) + ks * 32 + lg * 8) ^ ((lc & 7) << 3);
                bf16x8 ah = *(const bf16x8*)(cur + e0);
                bf16x8 al = *(const bf16x8*)(cur + 8192 + e0);
                acc[st][0] = __builtin_amdgcn_mfma_f32_16x16x32_bf16(ah, bh[ks][0], acc[st][0], 0, 0, 0);
                acc[st][0] = __builtin_amdgcn_mfma_f32_16x16x32_bf16(al, bh[ks][0], acc[st][0], 0, 0, 0);
                acc[st][0] = __builtin_amdgcn_mfma_f32_16x16x32_bf16(ah, bl[ks][0], acc[st][0], 0, 0, 0);
                acc[st][1] = __builtin_amdgcn_mfma_f32_16x16x32_bf16(ah, bh[ks][1], acc[st][1], 0, 0, 0);
                acc[st][1] = __builtin_amdgcn_mfma_f32_16x16x32_bf16(al, bh[ks][1], acc[st][1], 0, 0, 0);
                acc[st][1] = __builtin_amdgcn_mfma_f32_16x16x32_bf16(ah, bl[ks][1], acc[st][1], 0, 0, 0);
            }
        }

        // write staged data for round ro+1 into nxt
        if (ro < 3) {
#pragma unroll
            for (int k = 0; k < 4; ++k)
                *(uint4*)(nxt + std_[k]) = stg[k];
        }
        __syncthreads();
    }

    float m0 = -1e30f, m1 = -1e30f;
#pragma unroll
    for (int st = 0; st < 16; ++st)
#pragma unroll
        for (int r = 0; r < 4; ++r) {
            m0 = fmaxf(m0, acc[st][0][r]);
            m1 = fmaxf(m1, acc[st][1][r]);
        }
    m0 = fmaxf(m0, __shfl_xor(m0, 16)); m0 = fmaxf(m0, __shfl_xor(m0, 32));
    m1 = fmaxf(m1, __shfl_xor(m1, 16)); m1 = fmaxf(m1, __shfl_xor(m1, 32));

    float s0 = 0.f, s1 = 0.f;
#pragma unroll
    for (int st = 0; st < 16; ++st)
#pragma unroll
        for (int r = 0; r < 4; ++r) {
            float e0 = __expf(2.f * (acc[st][0][r] - m0));
            float e1 = __expf(2.f * (acc[st][1][r] - m1));
            acc[st][0][r] = e0; acc[st][1][r] = e1;
            s0 += e0; s1 += e1;
        }
    s0 += __shfl_xor(s0, 16); s0 += __shfl_xor(s0, 32);
    s1 += __shfl_xor(s1, 16); s1 += __shfl_xor(s1, 32);
    float i0 = 1.f / s0, i1 = 1.f / s1;

    if (final_mode) {
        int nA = n0 + lc, nB = n0 + 16 + lc;
#pragma unroll
        for (int st = 0; st < 16; ++st)
#pragma unroll
            for (int r = 0; r < 4; ++r) {
                int s = st * 16 + lg * 4 + r;
                qf[(size_t)s * HW + nA] = acc[st][0][r] * i0;
                qf[(size_t)s * HW + nB] = acc[st][1][r] * i1;
            }
        return;
    }

    // hoist phase-3 B fragments: wave w covers c in [w*16, w*16+16)
    bf16x8 pb[8];
#pragma unroll
    for (int kc = 0; kc < 8; ++kc)
        pb[kc] = *(const bf16x8*)(pfch + (((size_t)((nblk >> 5) + kc)) << 12)
                                  + (w * 16 + lc) * 32 + lg * 8);

    // prologue: write quarter 0 into sA0.
    // Safe: sA0 was last READ in round 2 (completed before round-2's end
    // barrier); round 3 read sA1 and ended with a barrier.
#pragma unroll
    for (int s4 = 0; s4 < 4; ++s4) {
#pragma unroll
        for (int g = 0; g < 2; ++g) {
            float iv = g ? i1 : i0;
#pragma unroll
            for (int r = 0; r < 4; ++r) {
                int idx = ((s4 * 8 + w) * 64 + (g * 2 + (lc >> 3)) * 16 + lg * 4 + r) * 8 + (lc & 7);
                sA0[idx] = f2bf(acc[s4][g][r] * iv);
            }
        }
    }
    __syncthreads();

#pragma unroll
    for (int h = 0; h < 4; ++h) {
        unsigned short* curQ = (h & 1) ? sA1 : sA0;
        unsigned short* nxtQ = (h & 1) ? sA0 : sA1;

        // write quarter h+1 into the other buffer (overlaps compute of h)
        if (h < 3) {
#pragma unroll
            for (int s4 = 0; s4 < 4; ++s4) {
                const int st = (h + 1) * 4 + s4;
#pragma unroll
                for (int g = 0; g < 2; ++g) {
                    float iv = g ? i1 : i0;
#pragma unroll
                    for (int r = 0; r < 4; ++r) {
                        int idx = ((s4 * 8 + w) * 64 + (g * 2 + (lc >> 3)) * 16 + lg * 4 + r) * 8 + (lc & 7);
                        nxtQ[idx] = f2bf(acc[st][g][r] * iv);
                    }
                }
            }
        }

        // compute quarter h from curQ
        f32x4 a2[4];
#pragma unroll
        for (int i = 0; i < 4; ++i)
#pragma unroll
            for (int j = 0; j < 4; ++j) a2[i][j] = 0.f;

#pragma unroll
        for (int kc = 0; kc < 8; ++kc) {
#pragma unroll
            for (int s4 = 0; s4 < 4; ++s4) {
                bf16x8 afr = *(const bf16x8*)(curQ + ((size_t)(s4 * 8 + kc) * 64 + l) * 8);
                a2[s4] = __builtin_amdgcn_mfma_f32_16x16x32_bf16(afr, pb[kc], a2[s4], 0, 0, 0);
            }
        }

        float* out = cn_part + (size_t)blockIdx.x * 32768;
#pragma unroll
        for (int s4 = 0; s4 < 4; ++s4)
#pragma unroll
            for (int r = 0; r < 4; ++r) {
                int s = (h * 4 + s4) * 16 + lg * 4 + r;
                int c = w * 16 + lc;
                out[s * 128 + c] = a2[s4][r];
            }
        __syncthreads();
    }
}

// ---------------------------------------------------------------------------
extern "C" void kernel_launch(void* const* d_in, const int* in_sizes, int n_in,
                              void* d_out, int out_size, void* d_ws, size_t ws_size,
                              hipStream_t stream)
{
    const float* x     = (const float*)d_in[0];
    const float* s1k7  = (const float*)d_in[1];
    const float* s1k5  = (const float*)d_in[2];
    const float* s1k3  = (const float*)d_in[3];
    const float* s1g   = (const float*)d_in[5];
    const float* s1be  = (const float*)d_in[6];
    const float* s2k7  = (const float*)d_in[7];
    const float* s2k5  = (const float*)d_in[8];
    const float* s2k3  = (const float*)d_in[9];
    const float* s2g   = (const float*)d_in[11];
    const float* s2be  = (const float*)d_in[12];
    const float* s3k7  = (const float*)d_in[13];
    const float* s3k5  = (const float*)d_in[14];
    const float* s3k3  = (const float*)d_in[15];
    const float* s3g   = (const float*)d_in[17];
    const float* s3be  = (const float*)d_in[18];
    const float* outw  = (const float*)d_in[19];
    const float* outb  = (const float*)d_in[20];

    float* ws = (float*)d_ws;
    size_t off = 0;
    unsigned short* wT1h = (unsigned short*)(ws + off); off += 100352;
    unsigned short* wT1l = (unsigned short*)(ws + off); off += 100352;
    unsigned short* wT2h = (unsigned short*)(ws + off); off += 25088;
    unsigned short* wT2l = (unsigned short*)(ws + off); off += 25088;
    unsigned short* wT3h = (unsigned short*)(ws + off); off += 50176;
    unsigned short* wT3l = (unsigned short*)(ws + off); off += 50176;
    float* stats = ws + off; off += 192;
    float* bn    = ws + off; off += 192;
    float* cn_fin= ws + off; off += 32768;
    unsigned short* chiT = (unsigned short*)(ws + off); off += 16384;
    unsigned short* cloT = (unsigned short*)(ws + off); off += 16384;
    unsigned short* xTh  = (unsigned short*)(ws + off); off += 4194304;
    unsigned short* xTl  = (unsigned short*)(ws + off); off += 4194304;
    unsigned short* pfch = (unsigned short*)(ws + off); off += 4194304;
    unsigned short* a12H = (unsigned short*)(ws + off); off += 2097152;
    unsigned short* a12L = (unsigned short*)(ws + off); off += 2097152;

    char* ob = (char*)d_out;
    float* p0   = (float*)ob;
    float* p1   = (float*)(ob + (size_t)8 * 1024 * 1024);
    float* ysum = (float*)(ob + (size_t)16 * 1024 * 1024);
    float* cn_part = (float*)ob;
    float* qf = (float*)ob;
    unsigned short* a3H = (unsigned short*)(ob + (size_t)32 * 1024 * 1024);
    unsigned short* a3L = a3H + (size_t)HW * 32;

    hipMemsetAsync(stats, 0, 192 * sizeof(float), stream);
    wmerge_kernel<<<(49 * 4 * 1024 + 255) / 256, 256, 0, stream>>>(s1k7, s1k5, s1k3, 103, 4, wT1h, wT1l);
    wmerge_kernel<<<(49 * 1 * 1024 + 255) / 256, 256, 0, stream>>>(s2k7, s2k5, s2k3, 32, 1, wT2h, wT2l);
    wmerge_kernel<<<(49 * 2 * 1024 + 255) / 256, 256, 0, stream>>>(s3k7, s3k5, s3k3, 64, 2, wT3h, wT3l);

    transpose_kernel<<<1024, 256, 0, stream>>>(x, xTh, xTl, pfch);

    convm_kernel<<<dim3(256, 2), 256, 0, stream>>>(xTh, xTl, 128, wT1h, wT1l, 4,
                                                   0, 2, 0, 49, 2, 4, 0, 49, p0);
    reduce2_kernel<<<1024, 256, 0, stream>>>(p0, p1, ysum, stats + 0, stats + 32);
    bnp_kernel<<<1, 32, 0, stream>>>(stats + 0, stats + 32, s1g, s1be, bn + 0, bn + 32);
    bna_kernel<<<1024, 256, 0, stream>>>(ysum, bn + 0, bn + 32, a12H, a12L, 64, 0);

    convm_kernel<<<dim3(256, 2), 256, 0, stream>>>(a12H, a12L, 64, wT2h, wT2l, 1,
                                                   0, 1, 0, 25, 0, 1, 25, 49, p0);
    reduce2_kernel<<<1024, 256, 0, stream>>>(p0, p1, ysum, stats + 64, stats + 96);
    bnp_kernel<<<1, 32, 0, stream>>>(stats + 64, stats + 96, s2g, s2be, bn + 64, bn + 96);
    bna_kernel<<<1024, 256, 0, stream>>>(ysum, bn + 64, bn + 96, a12H, a12L, 64, 32);

    convm_kernel<<<dim3(256, 2), 256, 0, stream>>>(a12H, a12L, 64, wT3h, wT3l, 2,
                                                   0, 1, 0, 49, 1, 2, 0, 49, p0);
    reduce2_kernel<<<1024, 256, 0, stream>>>(p0, p1, ysum, stats + 128, stats + 160);
    bnp_kernel<<<1, 32, 0, stream>>>(stats + 128, stats + 160, s3g, s3be, bn + 128, bn + 160);
    bna_kernel<<<1024, 256, 0, stream>>>(ysum, bn + 128, bn + 160, a3H, a3L, 32, 0);

    feat_kernel<<<256, 256, 0, stream>>>(a12H, a12L, a3H, a3L, outw, outb, xTh, xTl, pfch);
    c0_kernel<<<256, 256, 0, stream>>>(xTh, xTl, cn_fin);
    prep_kernel<<<256, 128, 0, stream>>>(cn_fin, chiT, cloT, 1.f / 256.f);

    for (int it = 0; it < 5; ++it) {
        distcn_kernel<<<256, 512, 0, stream>>>(chiT, cloT, xTh, xTl, pfch, cn_part, qf, 0);
        redprep_kernel<<<256, 128, 0, stream>>>(cn_part, chiT, cloT);
    }
    distcn_kernel<<<256, 512, 0, stream>>>(chiT, cloT, xTh, xTl, pfch, cn_part, qf, 1);
}

// Round 16
// 476.941 us; speedup vs baseline: 1.4197x; 1.0520x over previous
//
#include <hip/hip_runtime.h>

#define HW 65536

typedef short bf16x8 __attribute__((ext_vector_type(8)));
typedef float f32x4 __attribute__((ext_vector_type(4)));
typedef unsigned short u16x8 __attribute__((ext_vector_type(8)));

__device__ inline unsigned short f2bf(float v) {
    unsigned u = __float_as_uint(v);
    unsigned r = (u + 0x7FFF + ((u >> 16) & 1)) >> 16;
    return (unsigned short)r;
}
__device__ inline float ubf(unsigned short h) {
    return __uint_as_float(((unsigned)h) << 16);
}
__device__ inline uint4 pack8(const unsigned short* p) {
    uint4 u;
    u.x = (unsigned)p[0] | ((unsigned)p[1] << 16);
    u.y = (unsigned)p[2] | ((unsigned)p[3] << 16);
    u.z = (unsigned)p[4] | ((unsigned)p[5] << 16);
    u.w = (unsigned)p[6] | ((unsigned)p[7] << 16);
    return u;
}
// pfch is tiled: offset(c, n) = (n>>5)*4096 + c*32 + (n&31)
__device__ inline size_t pfchoff(int c, int n) {
    return ((size_t)(n >> 5) << 12) + (c << 5) + (n & 31);
}

// ---------------------------------------------------------------------------
// Merge 7/5/3 kernels into one 7x7; emit bf16 hi/lo in A-FRAGMENT LANE ORDER.
// ---------------------------------------------------------------------------
__global__ void wmerge_kernel(const float* __restrict__ k7, const float* __restrict__ k5,
                              const float* __restrict__ k3, int Cin, int nch,
                              unsigned short* __restrict__ wTh, unsigned short* __restrict__ wTl)
{
    int idx = blockIdx.x * 256 + threadIdx.x;
    int total = 49 * nch * 1024;
    if (idx >= total) return;
    int e = idx & 7;
    int lane = (idx >> 3) & 63;
    int octile = (idx >> 9) & 1;
    int chunk = (idx >> 10) % nch;
    int tap = idx / (nch << 10);
    int oc = octile * 16 + (lane & 15);
    int ci = chunk * 32 + (lane >> 4) * 8 + e;
    int ky = tap / 7, kx = tap % 7;
    float v = 0.f;
    if (ci < Cin) {
        v = k7[(oc * Cin + ci) * 49 + tap];
        if (ky >= 1 && ky <= 5 && kx >= 1 && kx <= 5)
            v += k5[(oc * Cin + ci) * 25 + (ky - 1) * 5 + (kx - 1)];
        if (ky >= 2 && ky <= 4 && kx >= 2 && kx <= 4)
            v += k3[(oc * Cin + ci) * 9 + (ky - 2) * 3 + (kx - 2)];
    }
    unsigned short h = f2bf(v);
    wTh[idx] = h;
    wTl[idx] = f2bf(v - ubf(h));
}

// ---------------------------------------------------------------------------
// x [103][HW] fp32 -> xT [n][128] bf16 hi/lo and pfch (tiled) rows 0..102
// ---------------------------------------------------------------------------
__global__ __launch_bounds__(256) void transpose_kernel(
    const float* __restrict__ x,
    unsigned short* __restrict__ xTh, unsigned short* __restrict__ xTl,
    unsigned short* __restrict__ pfch)
{
    __shared__ float buf[64 * 105];
    int t = threadIdx.x;
    int px0 = blockIdx.x * 64;
    for (int i = t; i < 103 * 64; i += 256) {
        int c = i >> 6, lane = i & 63;
        int n = px0 + lane;
        float v = x[(size_t)c * HW + n];
        buf[lane * 105 + c] = v;
        pfch[pfchoff(c, n)] = f2bf(v);
    }
    __syncthreads();
    int px = t >> 2, seg = t & 3;
    unsigned short h[32], l[32];
#pragma unroll
    for (int j = 0; j < 32; ++j) {
        int c = seg * 32 + j;
        float v = (c < 103) ? buf[px * 105 + c] : 0.f;
        h[j] = f2bf(v);
        l[j] = f2bf(v - ubf(h[j]));
    }
    size_t base = (size_t)(px0 + px) * 128 + seg * 32;
#pragma unroll
    for (int k = 0; k < 4; ++k) {
        *(uint4*)(xTh + base + k * 8) = pack8(h + k * 8);
        *(uint4*)(xTl + base + k * 8) = pack8(l + k * 8);
    }
}

// ---------------------------------------------------------------------------
// Implicit-GEMM 7x7 conv, MFMA 16x16x32 bf16, 3-phase hi/lo.
// 4 rows per wave (16-row block tile). Weights in LDS 3-tap ring.
// Grid (256, 2) with z-split work ranges. XCD-aware tile swizzle.
// ---------------------------------------------------------------------------
__global__ __launch_bounds__(256) void convm_kernel(
    const unsigned short* __restrict__ actH, const unsigned short* __restrict__ actL,
    int Cs,
    const unsigned short* __restrict__ wTh, const unsigned short* __restrict__ wTl,
    int nchw,
    int c0a, int c1a, int t0a, int t1a,
    int c0b, int c1b, int t0b, int t1b,
    float* __restrict__ ypart)
{
    __shared__ __align__(16) unsigned short sH[22 * 704];
    __shared__ __align__(16) unsigned short sL[22 * 704];
    __shared__ __align__(16) unsigned short sW[3 * 2048];
    int t = threadIdx.x;
    int w = t >> 6, l = t & 63;
    int lc = l & 15, lg = l >> 4;
    int bid = blockIdx.x;
    int swz = (bid & 7) * 32 + (bid >> 3);   // bijective: 256 = 8 XCDs x 32
    int bx = swz & 15, byy = swz >> 4;
    int x0 = bx * 16, y0 = byy * 16;
    int z = blockIdx.y;
    int ch0 = z ? c0b : c0a, ch1 = z ? c1b : c1a;
    int tap0 = z ? t0b : t0a, tap1 = z ? t1b : t1a;
    float* yp = ypart + (size_t)z * 32 * HW;

    f32x4 a_hh[2][4], a_lh[2][4], a_hl[2][4];   // [oc-tile][row]
#pragma unroll
    for (int ot = 0; ot < 2; ++ot)
#pragma unroll
        for (int rr = 0; rr < 4; ++rr)
#pragma unroll
            for (int r = 0; r < 4; ++r) {
                a_hh[ot][rr][r] = 0.f; a_lh[ot][rr][r] = 0.f; a_hl[ot][rr][r] = 0.f;
            }

    for (int ch = ch0; ch < ch1; ++ch) {
        int ci0 = ch * 32;
        __syncthreads();                // protect sH/sL from prior reads
        for (int i = t; i < 2 * 22 * 88; i += 256) {
            int pl = (i >= 22 * 88) ? 1 : 0;
            int j = pl ? i - 22 * 88 : i;
            int row = j / 88;
            int rem = j - row * 88;
            int px = rem >> 2, q = rem & 3;
            int gy = y0 - 3 + row, gx = x0 - 3 + px;
            uint4 v = {0u, 0u, 0u, 0u};
            if (gy >= 0 && gy < 256 && gx >= 0 && gx < 256) {
                const unsigned short* src = pl ? actL : actH;
                v = *(const uint4*)(src + (size_t)(gy * 256 + gx) * Cs + ci0 + q * 8);
            }
            unsigned short* dst = pl ? sL : sH;
            *(uint4*)(dst + row * 704 + q * 176 + px * 8) = v;
        }

        for (int g = tap0; g < tap1; g += 3) {
            int ge = g + 3; if (ge > tap1) ge = tap1;
            if (g > tap0) __syncthreads();      // protect sW from prior group reads
            for (int i = t; i < (ge - g) * 256; i += 256) {
                int tp = i >> 8, r = i & 255;
                const unsigned short* src = (r < 128) ? wTh : wTl;
                *(uint4*)(sW + tp * 2048 + r * 8) =
                    *(const uint4*)(src + ((size_t)((g + tp) * nchw + ch)) * 1024 + (r & 127) * 8);
            }
            __syncthreads();

            for (int tap = g; tap < ge; ++tap) {
                const unsigned short* wb = sW + (tap - g) * 2048 + l * 8;
                bf16x8 ah0 = *(const bf16x8*)(wb);
                bf16x8 ah1 = *(const bf16x8*)(wb + 512);
                bf16x8 al0 = *(const bf16x8*)(wb + 1024);
                bf16x8 al1 = *(const bf16x8*)(wb + 1536);
                int ky = tap / 7;
                int kx = tap - ky * 7;
#pragma unroll
                for (int rr = 0; rr < 4; ++rr) {
                    int off = (w * 4 + rr + ky) * 704 + lg * 176 + (lc + kx) * 8;
                    bf16x8 xh = *(const bf16x8*)(sH + off);
                    bf16x8 xl = *(const bf16x8*)(sL + off);
                    a_hh[0][rr] = __builtin_amdgcn_mfma_f32_16x16x32_bf16(ah0, xh, a_hh[0][rr], 0, 0, 0);
                    a_hh[1][rr] = __builtin_amdgcn_mfma_f32_16x16x32_bf16(ah1, xh, a_hh[1][rr], 0, 0, 0);
                    a_lh[0][rr] = __builtin_amdgcn_mfma_f32_16x16x32_bf16(al0, xh, a_lh[0][rr], 0, 0, 0);
                    a_lh[1][rr] = __builtin_amdgcn_mfma_f32_16x16x32_bf16(al1, xh, a_lh[1][rr], 0, 0, 0);
                    a_hl[0][rr] = __builtin_amdgcn_mfma_f32_16x16x32_bf16(ah0, xl, a_hl[0][rr], 0, 0, 0);
                    a_hl[1][rr] = __builtin_amdgcn_mfma_f32_16x16x32_bf16(ah1, xl, a_hl[1][rr], 0, 0, 0);
                }
            }
        }
    }

#pragma unroll
    for (int ot = 0; ot < 2; ++ot)
#pragma unroll
        for (int rr = 0; rr < 4; ++rr) {
            int n = (y0 + w * 4 + rr) * 256 + x0 + lc;
#pragma unroll
            for (int r = 0; r < 4; ++r) {
                int oc = ot * 16 + lg * 4 + r;
                yp[(size_t)oc * HW + n] = a_hh[ot][rr][r] + a_lh[ot][rr][r] + a_hl[ot][rr][r];
            }
        }
}

// ---------------------------------------------------------------------------
// Sum 2 partial planes -> ysum, with fused per-channel sum/sumsq stats.
// ---------------------------------------------------------------------------
__global__ __launch_bounds__(256) void reduce2_kernel(
    const float* __restrict__ p0, const float* __restrict__ p1,
    float* __restrict__ y, float* __restrict__ ssum, float* __restrict__ ssq)
{
    int c = blockIdx.x >> 5, seg = blockIdx.x & 31;
    int base = c * HW + seg * 2048 + threadIdx.x * 8;
    float s = 0.f, q = 0.f;
#pragma unroll
    for (int h = 0; h < 2; ++h) {
        int o = base + h * 4;
        float4 a0 = *(const float4*)&p0[o];
        float4 a1 = *(const float4*)&p1[o];
        float4 v;
        v.x = a0.x + a1.x; v.y = a0.y + a1.y;
        v.z = a0.z + a1.z; v.w = a0.w + a1.w;
        *(float4*)&y[o] = v;
        s += v.x + v.y + v.z + v.w;
        q = fmaf(v.x, v.x, q); q = fmaf(v.y, v.y, q);
        q = fmaf(v.z, v.z, q); q = fmaf(v.w, v.w, q);
    }
#pragma unroll
    for (int d = 32; d >= 1; d >>= 1) {
        s += __shfl_down(s, d);
        q += __shfl_down(q, d);
    }
    __shared__ float ls[4], lq[4];
    int w = threadIdx.x >> 6;
    if ((threadIdx.x & 63) == 0) { ls[w] = s; lq[w] = q; }
    __syncthreads();
    if (threadIdx.x == 0) {
        atomicAdd(&ssum[c], ls[0] + ls[1] + ls[2] + ls[3]);
        atomicAdd(&ssq[c], lq[0] + lq[1] + lq[2] + lq[3]);
    }
}

// ---------------------------------------------------------------------------
// BN(params recomputed in-block from stats) + ReLU + channel-last bf16 hi/lo
// ---------------------------------------------------------------------------
__global__ __launch_bounds__(256) void bna_kernel(
    const float* __restrict__ yraw,
    const float* __restrict__ ssum, const float* __restrict__ ssq,
    const float* __restrict__ g, const float* __restrict__ beta,
    unsigned short* __restrict__ aH, unsigned short* __restrict__ aL, int Cs, int slot0)
{
    __shared__ float scl[32], shf[32];
    int t = threadIdx.x;
    if (t < 32) {
        float mu  = ssum[t] * (1.f / 65536.f);
        float var = ssq[t] * (1.f / 65536.f) - mu * mu;
        float s = g[t] * rsqrtf(var + 1e-5f);
        scl[t] = s;
        shf[t] = beta[t] - mu * s;
    }
    __syncthreads();
    int lane = t & 63, cg = t >> 6;
    int px = blockIdx.x * 64 + lane;
    unsigned short h[8], l[8];
#pragma unroll
    for (int j = 0; j < 8; ++j) {
        int c = cg * 8 + j;
        float v = fmaxf(yraw[(size_t)c * HW + px] * scl[c] + shf[c], 0.f);
        h[j] = f2bf(v);
        l[j] = f2bf(v - ubf(h[j]));
    }
    *(uint4*)(aH + (size_t)px * Cs + slot0 + cg * 8) = pack8(h);
    *(uint4*)(aL + (size_t)px * Cs + slot0 + cg * 8) = pack8(l);
}

// ---------------------------------------------------------------------------
// 1x1 conv (96->15) + ReLU; writes pf slots 103..127 of xT and pfch (tiled)
// ---------------------------------------------------------------------------
__global__ __launch_bounds__(256) void feat_kernel(
    const unsigned short* __restrict__ a12H, const unsigned short* __restrict__ a12L,
    const unsigned short* __restrict__ a3H, const unsigned short* __restrict__ a3L,
    const float* __restrict__ w, const float* __restrict__ b,
    unsigned short* __restrict__ xTh, unsigned short* __restrict__ xTl,
    unsigned short* __restrict__ pfch)
{
    int n = blockIdx.x * 256 + threadIdx.x;
    float facc[15];
#pragma unroll
    for (int oc = 0; oc < 15; ++oc) facc[oc] = b[oc];

#pragma unroll
    for (int k = 0; k < 12; ++k) {
        uint4 uh, ul;
        if (k < 8) {
            uh = *(const uint4*)(a12H + (size_t)n * 64 + k * 8);
            ul = *(const uint4*)(a12L + (size_t)n * 64 + k * 8);
        } else {
            uh = *(const uint4*)(a3H + (size_t)n * 32 + (k - 8) * 8);
            ul = *(const uint4*)(a3L + (size_t)n * 32 + (k - 8) * 8);
        }
        unsigned hw_[4] = {uh.x, uh.y, uh.z, uh.w};
        unsigned lw_[4] = {ul.x, ul.y, ul.z, ul.w};
#pragma unroll
        for (int j = 0; j < 8; ++j) {
            unsigned short hh = (unsigned short)(hw_[j >> 1] >> ((j & 1) * 16));
            unsigned short ll = (unsigned short)(lw_[j >> 1] >> ((j & 1) * 16));
            float av = ubf(hh) + ubf(ll);
#pragma unroll
            for (int oc = 0; oc < 15; ++oc)
                facc[oc] = fmaf(av, w[oc * 96 + k * 8 + j], facc[oc]);
        }
    }
    unsigned short fh[16], fl[16];
#pragma unroll
    for (int oc = 0; oc < 15; ++oc) {
        float v = fmaxf(facc[oc], 0.f);
        fh[oc] = f2bf(v);
        fl[oc] = f2bf(v - ubf(fh[oc]));
    }
    fh[15] = 0; fl[15] = 0;

    size_t base = (size_t)n * 128;
    uint4 h0 = *(const uint4*)(xTh + base + 96);
    uint4 l0 = *(const uint4*)(xTl + base + 96);
    h0.w = (h0.w & 0xFFFFu) | ((unsigned)fh[0] << 16);
    l0.w = (l0.w & 0xFFFFu) | ((unsigned)fl[0] << 16);
    *(uint4*)(xTh + base + 96) = h0;
    *(uint4*)(xTl + base + 96) = l0;
    *(uint4*)(xTh + base + 104) = pack8(fh + 1);
    *(uint4*)(xTl + base + 104) = pack8(fl + 1);
    unsigned short t2h[8], t2l[8];
#pragma unroll
    for (int j = 0; j < 8; ++j) {
        t2h[j] = (j < 6) ? fh[9 + j] : (unsigned short)0;
        t2l[j] = (j < 6) ? fl[9 + j] : (unsigned short)0;
    }
    *(uint4*)(xTh + base + 112) = pack8(t2h);
    *(uint4*)(xTl + base + 112) = pack8(t2l);
    unsigned short t3h[8] = {0, 0, 0, 0, 0, 0, 0, 0x3F80};
    unsigned short t3l[8] = {0, 0, 0, 0, 0, 0, 0, 0};
    *(uint4*)(xTh + base + 120) = pack8(t3h);
    *(uint4*)(xTl + base + 120) = pack8(t3l);

#pragma unroll
    for (int k2 = 0; k2 < 15; ++k2)
        pfch[pfchoff(103 + k2, n)] = fh[k2];
    pfch[pfchoff(118, n)] = 0x3F80;
#pragma unroll
    for (int c = 119; c < 128; ++c)
        pfch[pfchoff(c, n)] = 0;
}

// ---------------------------------------------------------------------------
// c0: per-superpixel channel sums -> cn_fin[s][128]
// ---------------------------------------------------------------------------
__global__ __launch_bounds__(256) void c0_kernel(
    const unsigned short* __restrict__ pfTh, const unsigned short* __restrict__ pfTl,
    float* __restrict__ cn_fin)
{
    int s = blockIdx.x;
    int sy = s >> 4, sx = s & 15;
    int t = threadIdx.x;
    int xx = t >> 4;
    int cs = (t & 15) * 8;

    float acc[8];
#pragma unroll
    for (int j = 0; j < 8; ++j) acc[j] = 0.f;

    for (int yy = 0; yy < 16; ++yy) {
        int n = (sy * 16 + yy) * 256 + sx * 16 + xx;
        u16x8 h = *(const u16x8*)(pfTh + (size_t)n * 128 + cs);
        u16x8 l = *(const u16x8*)(pfTl + (size_t)n * 128 + cs);
#pragma unroll
        for (int j = 0; j < 8; ++j)
            acc[j] += ubf(h[j]) + ubf(l[j]);
    }
#pragma unroll
    for (int j = 0; j < 8; ++j) {
        acc[j] += __shfl_xor(acc[j], 16);
        acc[j] += __shfl_xor(acc[j], 32);
    }
    __shared__ float red[4][128];
    int w = t >> 6;
    if ((t & 63) < 16) {
#pragma unroll
        for (int j = 0; j < 8; ++j)
            red[w][(t & 15) * 8 + j] = acc[j];
    }
    __syncthreads();
    if (t < 128)
        cn_fin[s * 128 + t] = red[0][t] + red[1][t] + red[2][t] + red[3][t];
}

// ---------------------------------------------------------------------------
// prep (init only): centroids from c0 sums -> chiT/cloT; slot 127 = -0.5|c|^2
// ---------------------------------------------------------------------------
__global__ __launch_bounds__(128) void prep_kernel(
    const float* __restrict__ src,
    unsigned short* __restrict__ chiT, unsigned short* __restrict__ cloT,
    float scale0)
{
    int s = blockIdx.x, c = threadIdx.x;
    float v = src[s * 128 + c];
    v = (c < 118) ? v * scale0 : 0.f;
    float a = v * v;
#pragma unroll
    for (int d = 1; d < 64; d <<= 1) a += __shfl_xor(a, d);
    __shared__ float red[2];
    if ((c & 63) == 0) red[c >> 6] = a;
    __syncthreads();
    float tot = red[0] + red[1];
    unsigned short h, lo;
    if (c == 127) {
        float m2 = -0.5f * tot;
        h = f2bf(m2);
        lo = f2bf(m2 - ubf(h));
    } else {
        h = f2bf(v);
        lo = f2bf(v - ubf(h));
    }
    chiT[s * 128 + c] = h;
    cloT[s * 128 + c] = lo;
}

// ---------------------------------------------------------------------------
// redprep: sum 256 cn_part slices for one superpixel + prep, 4-way k-parallel.
// Grid 256 (s). Block 512: thread (c = t&127, kg = t>>7) sums 64 slices;
// LDS reduce 4 -> 1; then prep math (unchanged).
// ---------------------------------------------------------------------------
__global__ __launch_bounds__(512) void redprep_kernel(
    const float* __restrict__ cn_part,
    unsigned short* __restrict__ chiT, unsigned short* __restrict__ cloT)
{
    int s = blockIdx.x;
    int t = threadIdx.x;
    int c = t & 127, kg = t >> 7;
    float a = 0.f;
    const float* srcp = cn_part + (size_t)(kg * 64) * 32768 + s * 128 + c;
#pragma unroll 8
    for (int k = 0; k < 64; ++k)
        a += srcp[(size_t)k * 32768];
    __shared__ float part[4][128];
    part[kg][c] = a;
    __syncthreads();
    if (t >= 128) return;
    a = part[0][c] + part[1][c] + part[2][c] + part[3][c];
    __shared__ float sums[128];
    sums[c] = a;
    __syncthreads();
    float inv = 1.f / (sums[118] + 1e-8f);
    float v = (c < 118) ? a * inv : 0.f;
    float q = v * v;
#pragma unroll
    for (int d = 1; d < 64; d <<= 1) q += __shfl_xor(q, d);
    __shared__ float red[2];
    if ((c & 63) == 0) red[c >> 6] = q;
    __syncthreads();
    float tot = red[0] + red[1];
    unsigned short h, lo;
    if (c == 127) {
        float m2 = -0.5f * tot;
        h = f2bf(m2);
        lo = f2bf(m2 - ubf(h));
    } else {
        h = f2bf(v);
        lo = f2bf(v - ubf(h));
    }
    chiT[s * 128 + c] = h;
    cloT[s * 128 + c] = lo;
}

// ---------------------------------------------------------------------------
// FUSED dist+cn, double-buffered (unchanged from R15).
// ---------------------------------------------------------------------------
__global__ __launch_bounds__(512) void distcn_kernel(
    const unsigned short* __restrict__ chiT, const unsigned short* __restrict__ cloT,
    const unsigned short* __restrict__ pfTh, const unsigned short* __restrict__ pfTl,
    const unsigned short* __restrict__ pfch,
    float* __restrict__ cn_part, float* __restrict__ qf, int final_mode)
{
    __shared__ __align__(16) unsigned short sA0[16384];
    __shared__ __align__(16) unsigned short sA1[16384];
    int t = threadIdx.x;
    int w = t >> 6, l = t & 63;
    int lc = l & 15, lg = l >> 4;
    int nblk = blockIdx.x * 256;
    int n0 = nblk + w * 32;

    bf16x8 bh[4][2], bl[4][2];
#pragma unroll
    for (int ks = 0; ks < 4; ++ks) {
        int kb = ks * 32 + 8 * lg;
        bh[ks][0] = *(const bf16x8*)(pfTh + (size_t)(n0 + lc) * 128 + kb);
        bh[ks][1] = *(const bf16x8*)(pfTh + (size_t)(n0 + 16 + lc) * 128 + kb);
        bl[ks][0] = *(const bf16x8*)(pfTl + (size_t)(n0 + lc) * 128 + kb);
        bl[ks][1] = *(const bf16x8*)(pfTl + (size_t)(n0 + 16 + lc) * 128 + kb);
    }

    int sti[4], std_[4];
#pragma unroll
    for (int k = 0; k < 4; ++k) {
        int i = t + k * 512;
        int plane = i >> 10;
        int ii = i & 1023;
        int sl = ii >> 4;
        int j = ii & 15;
        sti[k] = (plane << 16) | (sl << 4) | j;
        std_[k] = plane * 8192 + (((sl << 7) + j * 8) ^ ((sl & 7) << 3));
    }

    f32x4 acc[16][2];
#pragma unroll
    for (int i = 0; i < 16; ++i)
#pragma unroll
        for (int g = 0; g < 2; ++g)
#pragma unroll
            for (int j = 0; j < 4; ++j) acc[i][g][j] = 0.f;

    {
#pragma unroll
        for (int k = 0; k < 4; ++k) {
            int plane = sti[k] >> 16;
            int sl = (sti[k] >> 4) & 0xFFF;
            int j = sti[k] & 15;
            const unsigned short* src = plane ? cloT : chiT;
            uint4 v = *(const uint4*)(src + (((size_t)sl) << 7) + j * 8);
            *(uint4*)(sA0 + std_[k]) = v;
        }
    }
    __syncthreads();

#pragma unroll
    for (int ro = 0; ro < 4; ++ro) {
        unsigned short* cur = (ro & 1) ? sA1 : sA0;
        unsigned short* nxt = (ro & 1) ? sA0 : sA1;

        uint4 stg[4];
        if (ro < 3) {
#pragma unroll
            for (int k = 0; k < 4; ++k) {
                int plane = sti[k] >> 16;
                int sl = (sti[k] >> 4) & 0xFFF;
                int j = sti[k] & 15;
                const unsigned short* src = plane ? cloT : chiT;
                stg[k] = *(const uint4*)(src + (((size_t)((ro + 1) * 64 + sl)) << 7) + j * 8);
            }
        }

#pragma unroll
        for (int s4 = 0; s4 < 4; ++s4) {
            const int st = ro * 4 + s4;
#pragma unroll
            for (int ks = 0; ks < 4; ++ks) {
                int e0 = (((s4 * 16 + lc) << 7) + ks * 32 + lg * 8) ^ ((lc & 7) << 3);
                bf16x8 ah = *(const bf16x8*)(cur + e0);
                bf16x8 al = *(const bf16x8*)(cur + 8192 + e0);
                acc[st][0] = __builtin_amdgcn_mfma_f32_16x16x32_bf16(ah, bh[ks][0], acc[st][0], 0, 0, 0);
                acc[st][0] = __builtin_amdgcn_mfma_f32_16x16x32_bf16(al, bh[ks][0], acc[st][0], 0, 0, 0);
                acc[st][0] = __builtin_amdgcn_mfma_f32_16x16x32_bf16(ah, bl[ks][0], acc[st][0], 0, 0, 0);
                acc[st][1] = __builtin_amdgcn_mfma_f32_16x16x32_bf16(ah, bh[ks][1], acc[st][1], 0, 0, 0);
                acc[st][1] = __builtin_amdgcn_mfma_f32_16x16x32_bf16(al, bh[ks][1], acc[st][1], 0, 0, 0);
                acc[st][1] = __builtin_amdgcn_mfma_f32_16x16x32_bf16(ah, bl[ks][1], acc[st][1], 0, 0, 0);
            }
        }

        if (ro < 3) {
#pragma unroll
            for (int k = 0; k < 4; ++k)
                *(uint4*)(nxt + std_[k]) = stg[k];
        }
        __syncthreads();
    }

    float m0 = -1e30f, m1 = -1e30f;
#pragma unroll
    for (int st = 0; st < 16; ++st)
#pragma unroll
        for (int r = 0; r < 4; ++r) {
            m0 = fmaxf(m0, acc[st][0][r]);
            m1 = fmaxf(m1, acc[st][1][r]);
        }
    m0 = fmaxf(m0, __shfl_xor(m0, 16)); m0 = fmaxf(m0, __shfl_xor(m0, 32));
    m1 = fmaxf(m1, __shfl_xor(m1, 16)); m1 = fmaxf(m1, __shfl_xor(m1, 32));

    float s0 = 0.f, s1 = 0.f;
#pragma unroll
    for (int st = 0; st < 16; ++st)
#pragma unroll
        for (int r = 0; r < 4; ++r) {
            float e0 = __expf(2.f * (acc[st][0][r] - m0));
            float e1 = __expf(2.f * (acc[st][1][r] - m1));
            acc[st][0][r] = e0; acc[st][1][r] = e1;
            s0 += e0; s1 += e1;
        }
    s0 += __shfl_xor(s0, 16); s0 += __shfl_xor(s0, 32);
    s1 += __shfl_xor(s1, 16); s1 += __shfl_xor(s1, 32);
    float i0 = 1.f / s0, i1 = 1.f / s1;

    if (final_mode) {
        int nA = n0 + lc, nB = n0 + 16 + lc;
#pragma unroll
        for (int st = 0; st < 16; ++st)
#pragma unroll
            for (int r = 0; r < 4; ++r) {
                int s = st * 16 + lg * 4 + r;
                qf[(size_t)s * HW + nA] = acc[st][0][r] * i0;
                qf[(size_t)s * HW + nB] = acc[st][1][r] * i1;
            }
        return;
    }

    bf16x8 pb[8];
#pragma unroll
    for (int kc = 0; kc < 8; ++kc)
        pb[kc] = *(const bf16x8*)(pfch + (((size_t)((nblk >> 5) + kc)) << 12)
                                  + (w * 16 + lc) * 32 + lg * 8);

#pragma unroll
    for (int s4 = 0; s4 < 4; ++s4) {
#pragma unroll
        for (int g = 0; g < 2; ++g) {
            float iv = g ? i1 : i0;
#pragma unroll
            for (int r = 0; r < 4; ++r) {
                int idx = ((s4 * 8 + w) * 64 + (g * 2 + (lc >> 3)) * 16 + lg * 4 + r) * 8 + (lc & 7);
                sA0[idx] = f2bf(acc[s4][g][r] * iv);
            }
        }
    }
    __syncthreads();

#pragma unroll
    for (int h = 0; h < 4; ++h) {
        unsigned short* curQ = (h & 1) ? sA1 : sA0;
        unsigned short* nxtQ = (h & 1) ? sA0 : sA1;

        if (h < 3) {
#pragma unroll
            for (int s4 = 0; s4 < 4; ++s4) {
                const int st = (h + 1) * 4 + s4;
#pragma unroll
                for (int g = 0; g < 2; ++g) {
                    float iv = g ? i1 : i0;
#pragma unroll
                    for (int r = 0; r < 4; ++r) {
                        int idx = ((s4 * 8 + w) * 64 + (g * 2 + (lc >> 3)) * 16 + lg * 4 + r) * 8 + (lc & 7);
                        nxtQ[idx] = f2bf(acc[st][g][r] * iv);
                    }
                }
            }
        }

        f32x4 a2[4];
#pragma unroll
        for (int i = 0; i < 4; ++i)
#pragma unroll
            for (int j = 0; j < 4; ++j) a2[i][j] = 0.f;

#pragma unroll
        for (int kc = 0; kc < 8; ++kc) {
#pragma unroll
            for (int s4 = 0; s4 < 4; ++s4) {
                bf16x8 afr = *(const bf16x8*)(curQ + ((size_t)(s4 * 8 + kc) * 64 + l) * 8);
                a2[s4] = __builtin_amdgcn_mfma_f32_16x16x32_bf16(afr, pb[kc], a2[s4], 0, 0, 0);
            }
        }

        float* out = cn_part + (size_t)blockIdx.x * 32768;
#pragma unroll
        for (int s4 = 0; s4 < 4; ++s4)
#pragma unroll
            for (int r = 0; r < 4; ++r) {
                int s = (h * 4 + s4) * 16 + lg * 4 + r;
                int c = w * 16 + lc;
                out[s * 128 + c] = a2[s4][r];
            }
        __syncthreads();
    }
}

// ---------------------------------------------------------------------------
extern "C" void kernel_launch(void* const* d_in, const int* in_sizes, int n_in,
                              void* d_out, int out_size, void* d_ws, size_t ws_size,
                              hipStream_t stream)
{
    const float* x     = (const float*)d_in[0];
    const float* s1k7  = (const float*)d_in[1];
    const float* s1k5  = (const float*)d_in[2];
    const float* s1k3  = (const float*)d_in[3];
    const float* s1g   = (const float*)d_in[5];
    const float* s1be  = (const float*)d_in[6];
    const float* s2k7  = (const float*)d_in[7];
    const float* s2k5  = (const float*)d_in[8];
    const float* s2k3  = (const float*)d_in[9];
    const float* s2g   = (const float*)d_in[11];
    const float* s2be  = (const float*)d_in[12];
    const float* s3k7  = (const float*)d_in[13];
    const float* s3k5  = (const float*)d_in[14];
    const float* s3k3  = (const float*)d_in[15];
    const float* s3g   = (const float*)d_in[17];
    const float* s3be  = (const float*)d_in[18];
    const float* outw  = (const float*)d_in[19];
    const float* outb  = (const float*)d_in[20];

    float* ws = (float*)d_ws;
    size_t off = 0;
    unsigned short* wT1h = (unsigned short*)(ws + off); off += 100352;
    unsigned short* wT1l = (unsigned short*)(ws + off); off += 100352;
    unsigned short* wT2h = (unsigned short*)(ws + off); off += 25088;
    unsigned short* wT2l = (unsigned short*)(ws + off); off += 25088;
    unsigned short* wT3h = (unsigned short*)(ws + off); off += 50176;
    unsigned short* wT3l = (unsigned short*)(ws + off); off += 50176;
    float* stats = ws + off; off += 192;
    float* cn_fin= ws + off; off += 32768;
    unsigned short* chiT = (unsigned short*)(ws + off); off += 16384;
    unsigned short* cloT = (unsigned short*)(ws + off); off += 16384;
    unsigned short* xTh  = (unsigned short*)(ws + off); off += 4194304;
    unsigned short* xTl  = (unsigned short*)(ws + off); off += 4194304;
    unsigned short* pfch = (unsigned short*)(ws + off); off += 4194304;
    unsigned short* a12H = (unsigned short*)(ws + off); off += 2097152;
    unsigned short* a12L = (unsigned short*)(ws + off); off += 2097152;

    char* ob = (char*)d_out;
    float* p0   = (float*)ob;
    float* p1   = (float*)(ob + (size_t)8 * 1024 * 1024);
    float* ysum = (float*)(ob + (size_t)16 * 1024 * 1024);
    float* cn_part = (float*)ob;
    float* qf = (float*)ob;
    unsigned short* a3H = (unsigned short*)(ob + (size_t)32 * 1024 * 1024);
    unsigned short* a3L = a3H + (size_t)HW * 32;

    hipMemsetAsync(stats, 0, 192 * sizeof(float), stream);
    wmerge_kernel<<<(49 * 4 * 1024 + 255) / 256, 256, 0, stream>>>(s1k7, s1k5, s1k3, 103, 4, wT1h, wT1l);
    wmerge_kernel<<<(49 * 1 * 1024 + 255) / 256, 256, 0, stream>>>(s2k7, s2k5, s2k3, 32, 1, wT2h, wT2l);
    wmerge_kernel<<<(49 * 2 * 1024 + 255) / 256, 256, 0, stream>>>(s3k7, s3k5, s3k3, 64, 2, wT3h, wT3l);

    transpose_kernel<<<1024, 256, 0, stream>>>(x, xTh, xTl, pfch);

    convm_kernel<<<dim3(256, 2), 256, 0, stream>>>(xTh, xTl, 128, wT1h, wT1l, 4,
                                                   0, 2, 0, 49, 2, 4, 0, 49, p0);
    reduce2_kernel<<<1024, 256, 0, stream>>>(p0, p1, ysum, stats + 0, stats + 32);
    bna_kernel<<<1024, 256, 0, stream>>>(ysum, stats + 0, stats + 32, s1g, s1be, a12H, a12L, 64, 0);

    convm_kernel<<<dim3(256, 2), 256, 0, stream>>>(a12H, a12L, 64, wT2h, wT2l, 1,
                                                   0, 1, 0, 25, 0, 1, 25, 49, p0);
    reduce2_kernel<<<1024, 256, 0, stream>>>(p0, p1, ysum, stats + 64, stats + 96);
    bna_kernel<<<1024, 256, 0, stream>>>(ysum, stats + 64, stats + 96, s2g, s2be, a12H, a12L, 64, 32);

    convm_kernel<<<dim3(256, 2), 256, 0, stream>>>(a12H, a12L, 64, wT3h, wT3l, 2,
                                                   0, 1, 0, 49, 1, 2, 0, 49, p0);
    reduce2_kernel<<<1024, 256, 0, stream>>>(p0, p1, ysum, stats + 128, stats + 160);
    bna_kernel<<<1024, 256, 0, stream>>>(ysum, stats + 128, stats + 160, s3g, s3be, a3H, a3L, 32, 0);

    feat_kernel<<<256, 256, 0, stream>>>(a12H, a12L, a3H, a3L, outw, outb, xTh, xTl, pfch);
    c0_kernel<<<256, 256, 0, stream>>>(xTh, xTl, cn_fin);
    prep_kernel<<<256, 128, 0, stream>>>(cn_fin, chiT, cloT, 1.f / 256.f);

    for (int it = 0; it < 5; ++it) {
        distcn_kernel<<<256, 512, 0, stream>>>(chiT, cloT, xTh, xTl, pfch, cn_part, qf, 0);
        redprep_kernel<<<256, 512, 0, stream>>>(cn_part, chiT, cloT);
    }
    distcn_kernel<<<256, 512, 0, stream>>>(chiT, cloT, xTh, xTl, pfch, cn_part, qf, 1);
}

// Round 17
// 470.707 us; speedup vs baseline: 1.4385x; 1.0132x over previous
//
#include <hip/hip_runtime.h>

#define HW 65536

typedef short bf16x8 __attribute__((ext_vector_type(8)));
typedef float f32x4 __attribute__((ext_vector_type(4)));
typedef unsigned short u16x8 __attribute__((ext_vector_type(8)));

__device__ inline unsigned short f2bf(float v) {
    unsigned u = __float_as_uint(v);
    unsigned r = (u + 0x7FFF + ((u >> 16) & 1)) >> 16;
    return (unsigned short)r;
}
__device__ inline float ubf(unsigned short h) {
    return __uint_as_float(((unsigned)h) << 16);
}
__device__ inline uint4 pack8(const unsigned short* p) {
    uint4 u;
    u.x = (unsigned)p[0] | ((unsigned)p[1] << 16);
    u.y = (unsigned)p[2] | ((unsigned)p[3] << 16);
    u.z = (unsigned)p[4] | ((unsigned)p[5] << 16);
    u.w = (unsigned)p[6] | ((unsigned)p[7] << 16);
    return u;
}
// pfch is tiled: offset(c, n) = (n>>5)*4096 + c*32 + (n&31)
__device__ inline size_t pfchoff(int c, int n) {
    return ((size_t)(n >> 5) << 12) + (c << 5) + (n & 31);
}

// ---------------------------------------------------------------------------
// Merge 7/5/3 kernels into one 7x7; emit bf16 hi/lo in A-FRAGMENT LANE ORDER.
// ---------------------------------------------------------------------------
__global__ void wmerge_kernel(const float* __restrict__ k7, const float* __restrict__ k5,
                              const float* __restrict__ k3, int Cin, int nch,
                              unsigned short* __restrict__ wTh, unsigned short* __restrict__ wTl)
{
    int idx = blockIdx.x * 256 + threadIdx.x;
    int total = 49 * nch * 1024;
    if (idx >= total) return;
    int e = idx & 7;
    int lane = (idx >> 3) & 63;
    int octile = (idx >> 9) & 1;
    int chunk = (idx >> 10) % nch;
    int tap = idx / (nch << 10);
    int oc = octile * 16 + (lane & 15);
    int ci = chunk * 32 + (lane >> 4) * 8 + e;
    int ky = tap / 7, kx = tap % 7;
    float v = 0.f;
    if (ci < Cin) {
        v = k7[(oc * Cin + ci) * 49 + tap];
        if (ky >= 1 && ky <= 5 && kx >= 1 && kx <= 5)
            v += k5[(oc * Cin + ci) * 25 + (ky - 1) * 5 + (kx - 1)];
        if (ky >= 2 && ky <= 4 && kx >= 2 && kx <= 4)
            v += k3[(oc * Cin + ci) * 9 + (ky - 2) * 3 + (kx - 2)];
    }
    unsigned short h = f2bf(v);
    wTh[idx] = h;
    wTl[idx] = f2bf(v - ubf(h));
}

// ---------------------------------------------------------------------------
// x [103][HW] fp32 -> xT half-planes A=[n][64] (c 0..63), B=[n][64] (c 64..127)
// bf16 hi/lo, plus pfch (tiled) rows 0..102
// ---------------------------------------------------------------------------
__global__ __launch_bounds__(256) void transpose_kernel(
    const float* __restrict__ x,
    unsigned short* __restrict__ xTAh, unsigned short* __restrict__ xTAl,
    unsigned short* __restrict__ xTBh, unsigned short* __restrict__ xTBl,
    unsigned short* __restrict__ pfch)
{
    __shared__ float buf[64 * 105];
    int t = threadIdx.x;
    int px0 = blockIdx.x * 64;
    for (int i = t; i < 103 * 64; i += 256) {
        int c = i >> 6, lane = i & 63;
        int n = px0 + lane;
        float v = x[(size_t)c * HW + n];
        buf[lane * 105 + c] = v;
        pfch[pfchoff(c, n)] = f2bf(v);
    }
    __syncthreads();
    int px = t >> 2, seg = t & 3;
    unsigned short h[32], l[32];
#pragma unroll
    for (int j = 0; j < 32; ++j) {
        int c = seg * 32 + j;
        float v = (c < 103) ? buf[px * 105 + c] : 0.f;
        h[j] = f2bf(v);
        l[j] = f2bf(v - ubf(h[j]));
    }
    unsigned short* dh = (seg < 2) ? xTAh : xTBh;
    unsigned short* dl = (seg < 2) ? xTAl : xTBl;
    size_t base = (size_t)(px0 + px) * 64 + (seg & 1) * 32;
#pragma unroll
    for (int k = 0; k < 4; ++k) {
        *(uint4*)(dh + base + k * 8) = pack8(h + k * 8);
        *(uint4*)(dl + base + k * 8) = pack8(l + k * 8);
    }
}

// ---------------------------------------------------------------------------
// Implicit-GEMM 7x7 conv, MFMA 16x16x32 bf16, 3-phase hi/lo.
// 4 rows per wave (16-row block tile). Weights in LDS 3-tap ring.
// Grid (256, 2); per-z act-pointer pair + weight-chunk offset.
// ---------------------------------------------------------------------------
__global__ __launch_bounds__(256) void convm_kernel(
    const unsigned short* __restrict__ actHa, const unsigned short* __restrict__ actLa,
    const unsigned short* __restrict__ actHb, const unsigned short* __restrict__ actLb,
    int Cs,
    const unsigned short* __restrict__ wTh, const unsigned short* __restrict__ wTl,
    int nchw,
    int c0a, int c1a, int t0a, int t1a, int wca,
    int c0b, int c1b, int t0b, int t1b, int wcb,
    float* __restrict__ ypart)
{
    __shared__ __align__(16) unsigned short sH[22 * 704];
    __shared__ __align__(16) unsigned short sL[22 * 704];
    __shared__ __align__(16) unsigned short sW[3 * 2048];
    int t = threadIdx.x;
    int w = t >> 6, l = t & 63;
    int lc = l & 15, lg = l >> 4;
    int bid = blockIdx.x;
    int swz = (bid & 7) * 32 + (bid >> 3);   // bijective: 256 = 8 XCDs x 32
    int bx = swz & 15, byy = swz >> 4;
    int x0 = bx * 16, y0 = byy * 16;
    int z = blockIdx.y;
    const unsigned short* actH = z ? actHb : actHa;
    const unsigned short* actL = z ? actLb : actLa;
    int ch0 = z ? c0b : c0a, ch1 = z ? c1b : c1a;
    int tap0 = z ? t0b : t0a, tap1 = z ? t1b : t1a;
    int wc = z ? wcb : wca;
    float* yp = ypart + (size_t)z * 32 * HW;

    f32x4 a_hh[2][4], a_lh[2][4], a_hl[2][4];   // [oc-tile][row]
#pragma unroll
    for (int ot = 0; ot < 2; ++ot)
#pragma unroll
        for (int rr = 0; rr < 4; ++rr)
#pragma unroll
            for (int r = 0; r < 4; ++r) {
                a_hh[ot][rr][r] = 0.f; a_lh[ot][rr][r] = 0.f; a_hl[ot][rr][r] = 0.f;
            }

    for (int ch = ch0; ch < ch1; ++ch) {
        int ci0 = ch * 32;
        __syncthreads();                // protect sH/sL from prior reads
        for (int i = t; i < 2 * 22 * 88; i += 256) {
            int pl = (i >= 22 * 88) ? 1 : 0;
            int j = pl ? i - 22 * 88 : i;
            int row = j / 88;
            int rem = j - row * 88;
            int px = rem >> 2, q = rem & 3;
            int gy = y0 - 3 + row, gx = x0 - 3 + px;
            uint4 v = {0u, 0u, 0u, 0u};
            if (gy >= 0 && gy < 256 && gx >= 0 && gx < 256) {
                const unsigned short* src = pl ? actL : actH;
                v = *(const uint4*)(src + (size_t)(gy * 256 + gx) * Cs + ci0 + q * 8);
            }
            unsigned short* dst = pl ? sL : sH;
            *(uint4*)(dst + row * 704 + q * 176 + px * 8) = v;
        }

        for (int g = tap0; g < tap1; g += 3) {
            int ge = g + 3; if (ge > tap1) ge = tap1;
            if (g > tap0) __syncthreads();      // protect sW from prior group reads
            for (int i = t; i < (ge - g) * 256; i += 256) {
                int tp = i >> 8, r = i & 255;
                const unsigned short* src = (r < 128) ? wTh : wTl;
                *(uint4*)(sW + tp * 2048 + r * 8) =
                    *(const uint4*)(src + ((size_t)((g + tp) * nchw + ch + wc)) * 1024 + (r & 127) * 8);
            }
            __syncthreads();

            for (int tap = g; tap < ge; ++tap) {
                const unsigned short* wb = sW + (tap - g) * 2048 + l * 8;
                bf16x8 ah0 = *(const bf16x8*)(wb);
                bf16x8 ah1 = *(const bf16x8*)(wb + 512);
                bf16x8 al0 = *(const bf16x8*)(wb + 1024);
                bf16x8 al1 = *(const bf16x8*)(wb + 1536);
                int ky = tap / 7;
                int kx = tap - ky * 7;
#pragma unroll
                for (int rr = 0; rr < 4; ++rr) {
                    int off = (w * 4 + rr + ky) * 704 + lg * 176 + (lc + kx) * 8;
                    bf16x8 xh = *(const bf16x8*)(sH + off);
                    bf16x8 xl = *(const bf16x8*)(sL + off);
                    a_hh[0][rr] = __builtin_amdgcn_mfma_f32_16x16x32_bf16(ah0, xh, a_hh[0][rr], 0, 0, 0);
                    a_hh[1][rr] = __builtin_amdgcn_mfma_f32_16x16x32_bf16(ah1, xh, a_hh[1][rr], 0, 0, 0);
                    a_lh[0][rr] = __builtin_amdgcn_mfma_f32_16x16x32_bf16(al0, xh, a_lh[0][rr], 0, 0, 0);
                    a_lh[1][rr] = __builtin_amdgcn_mfma_f32_16x16x32_bf16(al1, xh, a_lh[1][rr], 0, 0, 0);
                    a_hl[0][rr] = __builtin_amdgcn_mfma_f32_16x16x32_bf16(ah0, xl, a_hl[0][rr], 0, 0, 0);
                    a_hl[1][rr] = __builtin_amdgcn_mfma_f32_16x16x32_bf16(ah1, xl, a_hl[1][rr], 0, 0, 0);
                }
            }
        }
    }

#pragma unroll
    for (int ot = 0; ot < 2; ++ot)
#pragma unroll
        for (int rr = 0; rr < 4; ++rr) {
            int n = (y0 + w * 4 + rr) * 256 + x0 + lc;
#pragma unroll
            for (int r = 0; r < 4; ++r) {
                int oc = ot * 16 + lg * 4 + r;
                yp[(size_t)oc * HW + n] = a_hh[ot][rr][r] + a_lh[ot][rr][r] + a_hl[ot][rr][r];
            }
        }
}

// ---------------------------------------------------------------------------
// Sum 2 partial planes -> ysum, with fused per-channel sum/sumsq stats.
// ---------------------------------------------------------------------------
__global__ __launch_bounds__(256) void reduce2_kernel(
    const float* __restrict__ p0, const float* __restrict__ p1,
    float* __restrict__ y, float* __restrict__ ssum, float* __restrict__ ssq)
{
    int c = blockIdx.x >> 5, seg = blockIdx.x & 31;
    int base = c * HW + seg * 2048 + threadIdx.x * 8;
    float s = 0.f, q = 0.f;
#pragma unroll
    for (int h = 0; h < 2; ++h) {
        int o = base + h * 4;
        float4 a0 = *(const float4*)&p0[o];
        float4 a1 = *(const float4*)&p1[o];
        float4 v;
        v.x = a0.x + a1.x; v.y = a0.y + a1.y;
        v.z = a0.z + a1.z; v.w = a0.w + a1.w;
        *(float4*)&y[o] = v;
        s += v.x + v.y + v.z + v.w;
        q = fmaf(v.x, v.x, q); q = fmaf(v.y, v.y, q);
        q = fmaf(v.z, v.z, q); q = fmaf(v.w, v.w, q);
    }
#pragma unroll
    for (int d = 32; d >= 1; d >>= 1) {
        s += __shfl_down(s, d);
        q += __shfl_down(q, d);
    }
    __shared__ float ls[4], lq[4];
    int w = threadIdx.x >> 6;
    if ((threadIdx.x & 63) == 0) { ls[w] = s; lq[w] = q; }
    __syncthreads();
    if (threadIdx.x == 0) {
        atomicAdd(&ssum[c], ls[0] + ls[1] + ls[2] + ls[3]);
        atomicAdd(&ssq[c], lq[0] + lq[1] + lq[2] + lq[3]);
    }
}

// ---------------------------------------------------------------------------
// BN(params recomputed in-block from stats) + ReLU + channel-last bf16 hi/lo
// ---------------------------------------------------------------------------
__global__ __launch_bounds__(256) void bna_kernel(
    const float* __restrict__ yraw,
    const float* __restrict__ ssum, const float* __restrict__ ssq,
    const float* __restrict__ g, const float* __restrict__ beta,
    unsigned short* __restrict__ aH, unsigned short* __restrict__ aL, int Cs, int slot0)
{
    __shared__ float scl[32], shf[32];
    int t = threadIdx.x;
    if (t < 32) {
        float mu  = ssum[t] * (1.f / 65536.f);
        float var = ssq[t] * (1.f / 65536.f) - mu * mu;
        float s = g[t] * rsqrtf(var + 1e-5f);
        scl[t] = s;
        shf[t] = beta[t] - mu * s;
    }
    __syncthreads();
    int lane = t & 63, cg = t >> 6;
    int px = blockIdx.x * 64 + lane;
    unsigned short h[8], l[8];
#pragma unroll
    for (int j = 0; j < 8; ++j) {
        int c = cg * 8 + j;
        float v = fmaxf(yraw[(size_t)c * HW + px] * scl[c] + shf[c], 0.f);
        h[j] = f2bf(v);
        l[j] = f2bf(v - ubf(h[j]));
    }
    *(uint4*)(aH + (size_t)px * Cs + slot0 + cg * 8) = pack8(h);
    *(uint4*)(aL + (size_t)px * Cs + slot0 + cg * 8) = pack8(l);
}

// ---------------------------------------------------------------------------
// 1x1 conv (96->15) + ReLU; writes pf slots 103..127 (bufB offs 32..63) and
// pfch (tiled) rows 103..127
// ---------------------------------------------------------------------------
__global__ __launch_bounds__(256) void feat_kernel(
    const unsigned short* __restrict__ a12H, const unsigned short* __restrict__ a12L,
    const unsigned short* __restrict__ a3H, const unsigned short* __restrict__ a3L,
    const float* __restrict__ w, const float* __restrict__ b,
    unsigned short* __restrict__ xTBh, unsigned short* __restrict__ xTBl,
    unsigned short* __restrict__ pfch)
{
    int n = blockIdx.x * 256 + threadIdx.x;
    float facc[15];
#pragma unroll
    for (int oc = 0; oc < 15; ++oc) facc[oc] = b[oc];

#pragma unroll
    for (int k = 0; k < 12; ++k) {
        uint4 uh, ul;
        if (k < 8) {
            uh = *(const uint4*)(a12H + (size_t)n * 64 + k * 8);
            ul = *(const uint4*)(a12L + (size_t)n * 64 + k * 8);
        } else {
            uh = *(const uint4*)(a3H + (size_t)n * 32 + (k - 8) * 8);
            ul = *(const uint4*)(a3L + (size_t)n * 32 + (k - 8) * 8);
        }
        unsigned hw_[4] = {uh.x, uh.y, uh.z, uh.w};
        unsigned lw_[4] = {ul.x, ul.y, ul.z, ul.w};
#pragma unroll
        for (int j = 0; j < 8; ++j) {
            unsigned short hh = (unsigned short)(hw_[j >> 1] >> ((j & 1) * 16));
            unsigned short ll = (unsigned short)(lw_[j >> 1] >> ((j & 1) * 16));
            float av = ubf(hh) + ubf(ll);
#pragma unroll
            for (int oc = 0; oc < 15; ++oc)
                facc[oc] = fmaf(av, w[oc * 96 + k * 8 + j], facc[oc]);
        }
    }
    unsigned short fh[16], fl[16];
#pragma unroll
    for (int oc = 0; oc < 15; ++oc) {
        float v = fmaxf(facc[oc], 0.f);
        fh[oc] = f2bf(v);
        fl[oc] = f2bf(v - ubf(fh[oc]));
    }
    fh[15] = 0; fl[15] = 0;

    // bufB: slots 96..127 live at offsets 32..63
    size_t base = (size_t)n * 64;
    uint4 h0 = *(const uint4*)(xTBh + base + 32);
    uint4 l0 = *(const uint4*)(xTBl + base + 32);
    h0.w = (h0.w & 0xFFFFu) | ((unsigned)fh[0] << 16);
    l0.w = (l0.w & 0xFFFFu) | ((unsigned)fl[0] << 16);
    *(uint4*)(xTBh + base + 32) = h0;
    *(uint4*)(xTBl + base + 32) = l0;
    *(uint4*)(xTBh + base + 40) = pack8(fh + 1);
    *(uint4*)(xTBl + base + 40) = pack8(fl + 1);
    unsigned short t2h[8], t2l[8];
#pragma unroll
    for (int j = 0; j < 8; ++j) {
        t2h[j] = (j < 6) ? fh[9 + j] : (unsigned short)0;
        t2l[j] = (j < 6) ? fl[9 + j] : (unsigned short)0;
    }
    *(uint4*)(xTBh + base + 48) = pack8(t2h);
    *(uint4*)(xTBl + base + 48) = pack8(t2l);
    unsigned short t3h[8] = {0, 0, 0, 0, 0, 0, 0, 0x3F80};
    unsigned short t3l[8] = {0, 0, 0, 0, 0, 0, 0, 0};
    *(uint4*)(xTBh + base + 56) = pack8(t3h);
    *(uint4*)(xTBl + base + 56) = pack8(t3l);

#pragma unroll
    for (int k2 = 0; k2 < 15; ++k2)
        pfch[pfchoff(103 + k2, n)] = fh[k2];
    pfch[pfchoff(118, n)] = 0x3F80;
#pragma unroll
    for (int c = 119; c < 128; ++c)
        pfch[pfchoff(c, n)] = 0;
}

// ---------------------------------------------------------------------------
// c0: per-superpixel channel sums -> cn_fin[s][128]
// ---------------------------------------------------------------------------
__global__ __launch_bounds__(256) void c0_kernel(
    const unsigned short* __restrict__ xTAh, const unsigned short* __restrict__ xTAl,
    const unsigned short* __restrict__ xTBh, const unsigned short* __restrict__ xTBl,
    float* __restrict__ cn_fin)
{
    int s = blockIdx.x;
    int sy = s >> 4, sx = s & 15;
    int t = threadIdx.x;
    int xx = t >> 4;
    int cs = (t & 15) * 8;
    const unsigned short* ph = (cs < 64) ? xTAh : xTBh;
    const unsigned short* pl = (cs < 64) ? xTAl : xTBl;
    int co = cs & 63;

    float acc[8];
#pragma unroll
    for (int j = 0; j < 8; ++j) acc[j] = 0.f;

    for (int yy = 0; yy < 16; ++yy) {
        int n = (sy * 16 + yy) * 256 + sx * 16 + xx;
        u16x8 h = *(const u16x8*)(ph + (size_t)n * 64 + co);
        u16x8 l = *(const u16x8*)(pl + (size_t)n * 64 + co);
#pragma unroll
        for (int j = 0; j < 8; ++j)
            acc[j] += ubf(h[j]) + ubf(l[j]);
    }
#pragma unroll
    for (int j = 0; j < 8; ++j) {
        acc[j] += __shfl_xor(acc[j], 16);
        acc[j] += __shfl_xor(acc[j], 32);
    }
    __shared__ float red[4][128];
    int w = t >> 6;
    if ((t & 63) < 16) {
#pragma unroll
        for (int j = 0; j < 8; ++j)
            red[w][(t & 15) * 8 + j] = acc[j];
    }
    __syncthreads();
    if (t < 128)
        cn_fin[s * 128 + t] = red[0][t] + red[1][t] + red[2][t] + red[3][t];
}

// ---------------------------------------------------------------------------
// prep (init only): centroids from c0 sums -> chiT/cloT; slot 127 = -0.5|c|^2
// ---------------------------------------------------------------------------
__global__ __launch_bounds__(128) void prep_kernel(
    const float* __restrict__ src,
    unsigned short* __restrict__ chiT, unsigned short* __restrict__ cloT,
    float scale0)
{
    int s = blockIdx.x, c = threadIdx.x;
    float v = src[s * 128 + c];
    v = (c < 118) ? v * scale0 : 0.f;
    float a = v * v;
#pragma unroll
    for (int d = 1; d < 64; d <<= 1) a += __shfl_xor(a, d);
    __shared__ float red[2];
    if ((c & 63) == 0) red[c >> 6] = a;
    __syncthreads();
    float tot = red[0] + red[1];
    unsigned short h, lo;
    if (c == 127) {
        float m2 = -0.5f * tot;
        h = f2bf(m2);
        lo = f2bf(m2 - ubf(h));
    } else {
        h = f2bf(v);
        lo = f2bf(v - ubf(h));
    }
    chiT[s * 128 + c] = h;
    cloT[s * 128 + c] = lo;
}

// ---------------------------------------------------------------------------
// redprep: sum 256 cn_part slices for one superpixel + prep, 4-way k-parallel.
// ---------------------------------------------------------------------------
__global__ __launch_bounds__(512) void redprep_kernel(
    const float* __restrict__ cn_part,
    unsigned short* __restrict__ chiT, unsigned short* __restrict__ cloT)
{
    int s = blockIdx.x;
    int t = threadIdx.x;
    int c = t & 127, kg = t >> 7;
    float a = 0.f;
    const float* srcp = cn_part + (size_t)(kg * 64) * 32768 + s * 128 + c;
#pragma unroll 8
    for (int k = 0; k < 64; ++k)
        a += srcp[(size_t)k * 32768];
    __shared__ float part[4][128];
    part[kg][c] = a;
    __syncthreads();
    if (t >= 128) return;
    a = part[0][c] + part[1][c] + part[2][c] + part[3][c];
    __shared__ float sums[128];
    sums[c] = a;
    __syncthreads();
    float inv = 1.f / (sums[118] + 1e-8f);
    float v = (c < 118) ? a * inv : 0.f;
    float q = v * v;
#pragma unroll
    for (int d = 1; d < 64; d <<= 1) q += __shfl_xor(q, d);
    __shared__ float red[2];
    if ((c & 63) == 0) red[c >> 6] = q;
    __syncthreads();
    float tot = red[0] + red[1];
    unsigned short h, lo;
    if (c == 127) {
        float m2 = -0.5f * tot;
        h = f2bf(m2);
        lo = f2bf(m2 - ubf(h));
    } else {
        h = f2bf(v);
        lo = f2bf(v - ubf(h));
    }
    chiT[s * 128 + c] = h;
    cloT[s * 128 + c] = lo;
}

// ---------------------------------------------------------------------------
// FUSED dist+cn, double-buffered; xT split into A/B half-planes.
// ---------------------------------------------------------------------------
__global__ __launch_bounds__(512) void distcn_kernel(
    const unsigned short* __restrict__ chiT, const unsigned short* __restrict__ cloT,
    const unsigned short* __restrict__ xTAh, const unsigned short* __restrict__ xTAl,
    const unsigned short* __restrict__ xTBh, const unsigned short* __restrict__ xTBl,
    const unsigned short* __restrict__ pfch,
    float* __restrict__ cn_part, float* __restrict__ qf, int final_mode)
{
    __shared__ __align__(16) unsigned short sA0[16384];
    __shared__ __align__(16) unsigned short sA1[16384];
    int t = threadIdx.x;
    int w = t >> 6, l = t & 63;
    int lc = l & 15, lg = l >> 4;
    int nblk = blockIdx.x * 256;
    int n0 = nblk + w * 32;

    bf16x8 bh[4][2], bl[4][2];
#pragma unroll
    for (int ks = 0; ks < 4; ++ks) {
        int kb = (ks * 32 + 8 * lg) & 63;
        const unsigned short* ph = (ks < 2) ? xTAh : xTBh;
        const unsigned short* pl = (ks < 2) ? xTAl : xTBl;
        bh[ks][0] = *(const bf16x8*)(ph + (size_t)(n0 + lc) * 64 + kb);
        bh[ks][1] = *(const bf16x8*)(ph + (size_t)(n0 + 16 + lc) * 64 + kb);
        bl[ks][0] = *(const bf16x8*)(pl + (size_t)(n0 + lc) * 64 + kb);
        bl[ks][1] = *(const bf16x8*)(pl + (size_t)(n0 + 16 + lc) * 64 + kb);
    }

    int sti[4], std_[4];
#pragma unroll
    for (int k = 0; k < 4; ++k) {
        int i = t + k * 512;
        int plane = i >> 10;
        int ii = i & 1023;
        int sl = ii >> 4;
        int j = ii & 15;
        sti[k] = (plane << 16) | (sl << 4) | j;
        std_[k] = plane * 8192 + (((sl << 7) + j * 8) ^ ((sl & 7) << 3));
    }

    f32x4 acc[16][2];
#pragma unroll
    for (int i = 0; i < 16; ++i)
#pragma unroll
        for (int g = 0; g < 2; ++g)
#pragma unroll
            for (int j = 0; j < 4; ++j) acc[i][g][j] = 0.f;

    {
#pragma unroll
        for (int k = 0; k < 4; ++k) {
            int plane = sti[k] >> 16;
            int sl = (sti[k] >> 4) & 0xFFF;
            int j = sti[k] & 15;
            const unsigned short* src = plane ? cloT : chiT;
            uint4 v = *(const uint4*)(src + (((size_t)sl) << 7) + j * 8);
            *(uint4*)(sA0 + std_[k]) = v;
        }
    }
    __syncthreads();

#pragma unroll
    for (int ro = 0; ro < 4; ++ro) {
        unsigned short* cur = (ro & 1) ? sA1 : sA0;
        unsigned short* nxt = (ro & 1) ? sA0 : sA1;

        uint4 stg[4];
        if (ro < 3) {
#pragma unroll
            for (int k = 0; k < 4; ++k) {
                int plane = sti[k] >> 16;
                int sl = (sti[k] >> 4) & 0xFFF;
                int j = sti[k] & 15;
                const unsigned short* src = plane ? cloT : chiT;
                stg[k] = *(const uint4*)(src + (((size_t)((ro + 1) * 64 + sl)) << 7) + j * 8);
            }
        }

#pragma unroll
        for (int s4 = 0; s4 < 4; ++s4) {
            const int st = ro * 4 + s4;
#pragma unroll
            for (int ks = 0; ks < 4; ++ks) {
                int e0 = (((s4 * 16 + lc) << 7) + ks * 32 + lg * 8) ^ ((lc & 7) << 3);
                bf16x8 ah = *(const bf16x8*)(cur + e0);
                bf16x8 al = *(const bf16x8*)(cur + 8192 + e0);
                acc[st][0] = __builtin_amdgcn_mfma_f32_16x16x32_bf16(ah, bh[ks][0], acc[st][0], 0, 0, 0);
                acc[st][0] = __builtin_amdgcn_mfma_f32_16x16x32_bf16(al, bh[ks][0], acc[st][0], 0, 0, 0);
                acc[st][0] = __builtin_amdgcn_mfma_f32_16x16x32_bf16(ah, bl[ks][0], acc[st][0], 0, 0, 0);
                acc[st][1] = __builtin_amdgcn_mfma_f32_16x16x32_bf16(ah, bh[ks][1], acc[st][1], 0, 0, 0);
                acc[st][1] = __builtin_amdgcn_mfma_f32_16x16x32_bf16(al, bh[ks][1], acc[st][1], 0, 0, 0);
                acc[st][1] = __builtin_amdgcn_mfma_f32_16x16x32_bf16(ah, bl[ks][1], acc[st][1], 0, 0, 0);
            }
        }

        if (ro < 3) {
#pragma unroll
            for (int k = 0; k < 4; ++k)
                *(uint4*)(nxt + std_[k]) = stg[k];
        }
        __syncthreads();
    }

    float m0 = -1e30f, m1 = -1e30f;
#pragma unroll
    for (int st = 0; st < 16; ++st)
#pragma unroll
        for (int r = 0; r < 4; ++r) {
            m0 = fmaxf(m0, acc[st][0][r]);
            m1 = fmaxf(m1, acc[st][1][r]);
        }
    m0 = fmaxf(m0, __shfl_xor(m0, 16)); m0 = fmaxf(m0, __shfl_xor(m0, 32));
    m1 = fmaxf(m1, __shfl_xor(m1, 16)); m1 = fmaxf(m1, __shfl_xor(m1, 32));

    float s0 = 0.f, s1 = 0.f;
#pragma unroll
    for (int st = 0; st < 16; ++st)
#pragma unroll
        for (int r = 0; r < 4; ++r) {
            float e0 = __expf(2.f * (acc[st][0][r] - m0));
            float e1 = __expf(2.f * (acc[st][1][r] - m1));
            acc[st][0][r] = e0; acc[st][1][r] = e1;
            s0 += e0; s1 += e1;
        }
    s0 += __shfl_xor(s0, 16); s0 += __shfl_xor(s0, 32);
    s1 += __shfl_xor(s1, 16); s1 += __shfl_xor(s1, 32);
    float i0 = 1.f / s0, i1 = 1.f / s1;

    if (final_mode) {
        int nA = n0 + lc, nB = n0 + 16 + lc;
#pragma unroll
        for (int st = 0; st < 16; ++st)
#pragma unroll
            for (int r = 0; r < 4; ++r) {
                int s = st * 16 + lg * 4 + r;
                qf[(size_t)s * HW + nA] = acc[st][0][r] * i0;
                qf[(size_t)s * HW + nB] = acc[st][1][r] * i1;
            }
        return;
    }

    bf16x8 pb[8];
#pragma unroll
    for (int kc = 0; kc < 8; ++kc)
        pb[kc] = *(const bf16x8*)(pfch + (((size_t)((nblk >> 5) + kc)) << 12)
                                  + (w * 16 + lc) * 32 + lg * 8);

#pragma unroll
    for (int s4 = 0; s4 < 4; ++s4) {
#pragma unroll
        for (int g = 0; g < 2; ++g) {
            float iv = g ? i1 : i0;
#pragma unroll
            for (int r = 0; r < 4; ++r) {
                int idx = ((s4 * 8 + w) * 64 + (g * 2 + (lc >> 3)) * 16 + lg * 4 + r) * 8 + (lc & 7);
                sA0[idx] = f2bf(acc[s4][g][r] * iv);
            }
        }
    }
    __syncthreads();

#pragma unroll
    for (int h = 0; h < 4; ++h) {
        unsigned short* curQ = (h & 1) ? sA1 : sA0;
        unsigned short* nxtQ = (h & 1) ? sA0 : sA1;

        if (h < 3) {
#pragma unroll
            for (int s4 = 0; s4 < 4; ++s4) {
                const int st = (h + 1) * 4 + s4;
#pragma unroll
                for (int g = 0; g < 2; ++g) {
                    float iv = g ? i1 : i0;
#pragma unroll
                    for (int r = 0; r < 4; ++r) {
                        int idx = ((s4 * 8 + w) * 64 + (g * 2 + (lc >> 3)) * 16 + lg * 4 + r) * 8 + (lc & 7);
                        nxtQ[idx] = f2bf(acc[st][g][r] * iv);
                    }
                }
            }
        }

        f32x4 a2[4];
#pragma unroll
        for (int i = 0; i < 4; ++i)
#pragma unroll
            for (int j = 0; j < 4; ++j) a2[i][j] = 0.f;

#pragma unroll
        for (int kc = 0; kc < 8; ++kc) {
#pragma unroll
            for (int s4 = 0; s4 < 4; ++s4) {
                bf16x8 afr = *(const bf16x8*)(curQ + ((size_t)(s4 * 8 + kc) * 64 + l) * 8);
                a2[s4] = __builtin_amdgcn_mfma_f32_16x16x32_bf16(afr, pb[kc], a2[s4], 0, 0, 0);
            }
        }

        float* out = cn_part + (size_t)blockIdx.x * 32768;
#pragma unroll
        for (int s4 = 0; s4 < 4; ++s4)
#pragma unroll
            for (int r = 0; r < 4; ++r) {
                int s = (h * 4 + s4) * 16 + lg * 4 + r;
                int c = w * 16 + lc;
                out[s * 128 + c] = a2[s4][r];
            }
        __syncthreads();
    }
}

// ---------------------------------------------------------------------------
extern "C" void kernel_launch(void* const* d_in, const int* in_sizes, int n_in,
                              void* d_out, int out_size, void* d_ws, size_t ws_size,
                              hipStream_t stream)
{
    const float* x     = (const float*)d_in[0];
    const float* s1k7  = (const float*)d_in[1];
    const float* s1k5  = (const float*)d_in[2];
    const float* s1k3  = (const float*)d_in[3];
    const float* s1g   = (const float*)d_in[5];
    const float* s1be  = (const float*)d_in[6];
    const float* s2k7  = (const float*)d_in[7];
    const float* s2k5  = (const float*)d_in[8];
    const float* s2k3  = (const float*)d_in[9];
    const float* s2g   = (const float*)d_in[11];
    const float* s2be  = (const float*)d_in[12];
    const float* s3k7  = (const float*)d_in[13];
    const float* s3k5  = (const float*)d_in[14];
    const float* s3k3  = (const float*)d_in[15];
    const float* s3g   = (const float*)d_in[17];
    const float* s3be  = (const float*)d_in[18];
    const float* outw  = (const float*)d_in[19];
    const float* outb  = (const float*)d_in[20];

    float* ws = (float*)d_ws;
    size_t off = 0;
    unsigned short* wT1h = (unsigned short*)(ws + off); off += 100352;
    unsigned short* wT1l = (unsigned short*)(ws + off); off += 100352;
    unsigned short* wT2h = (unsigned short*)(ws + off); off += 25088;
    unsigned short* wT2l = (unsigned short*)(ws + off); off += 25088;
    unsigned short* wT3h = (unsigned short*)(ws + off); off += 50176;
    unsigned short* wT3l = (unsigned short*)(ws + off); off += 50176;
    float* stats = ws + off; off += 192;
    float* cn_fin= ws + off; off += 32768;
    unsigned short* chiT = (unsigned short*)(ws + off); off += 16384;
    unsigned short* cloT = (unsigned short*)(ws + off); off += 16384;
    unsigned short* xTAh = (unsigned short*)(ws + off); off += 2097152;
    unsigned short* xTAl = (unsigned short*)(ws + off); off += 2097152;
    unsigned short* xTBh = (unsigned short*)(ws + off); off += 2097152;
    unsigned short* xTBl = (unsigned short*)(ws + off); off += 2097152;
    unsigned short* pfch = (unsigned short*)(ws + off); off += 4194304;
    unsigned short* a12H = (unsigned short*)(ws + off); off += 2097152;
    unsigned short* a12L = (unsigned short*)(ws + off); off += 2097152;

    char* ob = (char*)d_out;
    float* p0   = (float*)ob;
    float* p1   = (float*)(ob + (size_t)8 * 1024 * 1024);
    float* ysum = (float*)(ob + (size_t)16 * 1024 * 1024);
    float* cn_part = (float*)ob;
    float* qf = (float*)ob;
    unsigned short* a3H = (unsigned short*)(ob + (size_t)32 * 1024 * 1024);
    unsigned short* a3L = a3H + (size_t)HW * 32;

    hipMemsetAsync(stats, 0, 192 * sizeof(float), stream);
    wmerge_kernel<<<(49 * 4 * 1024 + 255) / 256, 256, 0, stream>>>(s1k7, s1k5, s1k3, 103, 4, wT1h, wT1l);
    wmerge_kernel<<<(49 * 1 * 1024 + 255) / 256, 256, 0, stream>>>(s2k7, s2k5, s2k3, 32, 1, wT2h, wT2l);
    wmerge_kernel<<<(49 * 2 * 1024 + 255) / 256, 256, 0, stream>>>(s3k7, s3k5, s3k3, 64, 2, wT3h, wT3l);

    transpose_kernel<<<1024, 256, 0, stream>>>(x, xTAh, xTAl, xTBh, xTBl, pfch);

    // stage 1: z=0 reads bufA (ci 0..63, weight chunks 0..1);
    //          z=1 reads bufB (ci 64..127, weight chunks 2..3)
    convm_kernel<<<dim3(256, 2), 256, 0, stream>>>(xTAh, xTAl, xTBh, xTBl, 64,
                                                   wT1h, wT1l, 4,
                                                   0, 2, 0, 49, 0,
                                                   0, 2, 0, 49, 2, p0);
    reduce2_kernel<<<1024, 256, 0, stream>>>(p0, p1, ysum, stats + 0, stats + 32);
    bna_kernel<<<1024, 256, 0, stream>>>(ysum, stats + 0, stats + 32, s1g, s1be, a12H, a12L, 64, 0);

    // stage 2: taps split across z; single 32-ci chunk
    convm_kernel<<<dim3(256, 2), 256, 0, stream>>>(a12H, a12L, a12H, a12L, 64,
                                                   wT2h, wT2l, 1,
                                                   0, 1, 0, 25, 0,
                                                   0, 1, 25, 49, 0, p0);
    reduce2_kernel<<<1024, 256, 0, stream>>>(p0, p1, ysum, stats + 64, stats + 96);
    bna_kernel<<<1024, 256, 0, stream>>>(ysum, stats + 64, stats + 96, s2g, s2be, a12H, a12L, 64, 32);

    // stage 3: z splits ci-chunks {0}/{1} of a12
    convm_kernel<<<dim3(256, 2), 256, 0, stream>>>(a12H, a12L, a12H, a12L, 64,
                                                   wT3h, wT3l, 2,
                                                   0, 1, 0, 49, 0,
                                                   1, 2, 0, 49, 0, p0);
    reduce2_kernel<<<1024, 256, 0, stream>>>(p0, p1, ysum, stats + 128, stats + 160);
    bna_kernel<<<1024, 256, 0, stream>>>(ysum, stats + 128, stats + 160, s3g, s3be, a3H, a3L, 32, 0);

    feat_kernel<<<256, 256, 0, stream>>>(a12H, a12L, a3H, a3L, outw, outb, xTBh, xTBl, pfch);
    c0_kernel<<<256, 256, 0, stream>>>(xTAh, xTAl, xTBh, xTBl, cn_fin);
    prep_kernel<<<256, 128, 0, stream>>>(cn_fin, chiT, cloT, 1.f / 256.f);

    for (int it = 0; it < 5; ++it) {
        distcn_kernel<<<256, 512, 0, stream>>>(chiT, cloT, xTAh, xTAl, xTBh, xTBl, pfch, cn_part, qf, 0);
        redprep_kernel<<<256, 512, 0, stream>>>(cn_part, chiT, cloT);
    }
    distcn_kernel<<<256, 512, 0, stream>>>(chiT, cloT, xTAh, xTAl, xTBh, xTBl, pfch, cn_part, qf, 1);
}